// Round 1
// baseline (1971.345 us; speedup 1.0000x reference)
//
#include <hip/hip_runtime.h>
#include <math.h>

#define NA 16384
#define NE 65536
#define AD 29

__device__ __forceinline__ float sigmoidf_(float x) { return 1.0f / (1.0f + expf(-x)); }

// ============ init h: pad atom features 29 -> 64 ============
__global__ void k_init_h(const float* __restrict__ af, float* __restrict__ h) {
  int idx = blockIdx.x * 256 + threadIdx.x;
  if (idx >= NA * 64) return;
  int a = idx >> 6, d = idx & 63;
  h[idx] = (d < AD) ? af[a * AD + d] : 0.0f;
}

// ============ edge message + scatter-add ============
// msg[e,i] = sum_j (sum_k bf[e,k]*K[k][i*64+j] + bias[i*64+j]) * h[dst_e][j]
// kernel+bias (144 KB) staged in LDS, XOR-swizzled so lane-strided b128 reads
// are conflict-free. EBLK edges per wave amortize the LDS reads.
#define EBLK 4
__global__ __launch_bounds__(256, 1) void k_edge(
    const float* __restrict__ bf, const int* __restrict__ pairs,
    const float* __restrict__ kern, const float* __restrict__ kbias,
    const float* __restrict__ h, float* __restrict__ agg) {
  __shared__ __align__(16) float ker_s[9 * 4096];      // 8 kernel slabs + bias slab
  __shared__ __align__(16) float nbr_s[4][EBLK][64];
  const int tid = threadIdx.x;
  const int lane = tid & 63;
  const int wv = tid >> 6;

  for (int idx = tid; idx < 9 * 4096; idx += 256) {
    int k = idx >> 12;
    int rem = idx & 4095;
    int i = rem >> 6, j = rem & 63;
    float v = (k < 8) ? kern[idx] : kbias[rem];
    ker_s[(k << 12) + (i << 6) + ((((j >> 2) ^ (i & 7)) << 2) | (j & 3))] = v;
  }
  __syncthreads();

  const float4* ks4 = reinterpret_cast<const float4*>(ker_s);
  const int swz = lane & 7;
  const int base = lane << 4;           // lane*16 float4s (row i = lane)
  const int gw = blockIdx.x * 4 + wv;
  const int stride = gridDim.x * 4 * EBLK;

  for (int eg = gw * EBLK; eg < NE; eg += stride) {
    float bval = 0.0f;
    if (lane < 8 * EBLK) bval = bf[(eg + (lane >> 3)) * 8 + (lane & 7)];
    float bfs[EBLK][8];
#pragma unroll
    for (int e = 0; e < EBLK; ++e)
#pragma unroll
      for (int k = 0; k < 8; ++k) bfs[e][k] = __shfl(bval, e * 8 + k, 64);

    int srcs[EBLK];
#pragma unroll
    for (int e = 0; e < EBLK; ++e) {
      int2 p = reinterpret_cast<const int2*>(pairs)[eg + e];
      srcs[e] = p.x;
      nbr_s[wv][e][lane] = h[p.y * 64 + lane];
    }
    __syncthreads();

    const float4* nb4 = reinterpret_cast<const float4*>(&nbr_s[wv][0][0]);
    float msg[EBLK] = {0.f, 0.f, 0.f, 0.f};
#pragma unroll
    for (int j4 = 0; j4 < 16; ++j4) {
      int slot = j4 ^ swz;
      float4 kv[8];
#pragma unroll
      for (int k = 0; k < 8; ++k) kv[k] = ks4[(k << 10) + base + slot];
      float4 bv = ks4[(8 << 10) + base + slot];
#pragma unroll
      for (int e = 0; e < EBLK; ++e) {
        float4 nb = nb4[e * 16 + j4];
        float4 m = bv;
#pragma unroll
        for (int k = 0; k < 8; ++k) {
          m.x = fmaf(bfs[e][k], kv[k].x, m.x);
          m.y = fmaf(bfs[e][k], kv[k].y, m.y);
          m.z = fmaf(bfs[e][k], kv[k].z, m.z);
          m.w = fmaf(bfs[e][k], kv[k].w, m.w);
        }
        msg[e] += m.x * nb.x + m.y * nb.y + m.z * nb.z + m.w * nb.w;
      }
    }
#pragma unroll
    for (int e = 0; e < EBLK; ++e) atomicAdd(&agg[srcs[e] * 64 + lane], msg[e]);
    __syncthreads();
  }
}

// ============ GRU cell (per atom) ============
#define GABLK 4
__global__ __launch_bounds__(256, 1) void k_gru(
    const float* __restrict__ agg, const float* __restrict__ wih,
    const float* __restrict__ whh, const float* __restrict__ bih,
    const float* __restrict__ bhh, float* __restrict__ h) {
  __shared__ __align__(16) float wih_s[192 * 64];
  __shared__ __align__(16) float whh_s[192 * 64];
  __shared__ __align__(16) float act_s[4][2][GABLK][64];
  const int tid = threadIdx.x, lane = tid & 63, wv = tid >> 6;

  for (int idx = tid; idx < 192 * 64; idx += 256) {
    int r = idx >> 6, d = idx & 63;
    int pos = (r << 6) + ((((d >> 2) ^ (r & 7)) << 2) | (d & 3));
    wih_s[pos] = wih[idx];
    whh_s[pos] = whh[idx];
  }
  __syncthreads();

  const float4* wi4 = reinterpret_cast<const float4*>(wih_s);
  const float4* wh4 = reinterpret_cast<const float4*>(whh_s);
  const float bir = bih[lane], biz = bih[64 + lane], bin_ = bih[128 + lane];
  const float bhr = bhh[lane], bhz = bhh[64 + lane], bhn = bhh[128 + lane];
  const int swz = lane & 7;
  const int gw = blockIdx.x * 4 + wv;
  const int stride = gridDim.x * 4 * GABLK;

  for (int ag = gw * GABLK; ag < NA; ag += stride) {
#pragma unroll
    for (int e = 0; e < GABLK; ++e) {
      act_s[wv][0][e][lane] = agg[(ag + e) * 64 + lane];
      act_s[wv][1][e][lane] = h[(ag + e) * 64 + lane];
    }
    __syncthreads();
    const float4* a4 = reinterpret_cast<const float4*>(&act_s[wv][0][0][0]);
    const float4* h4 = reinterpret_cast<const float4*>(&act_s[wv][1][0][0]);
    float air[GABLK] = {0,0,0,0}, aiz[GABLK] = {0,0,0,0}, ain[GABLK] = {0,0,0,0};
    float ahr[GABLK] = {0,0,0,0}, ahz[GABLK] = {0,0,0,0}, ahn[GABLK] = {0,0,0,0};
#pragma unroll
    for (int d4 = 0; d4 < 16; ++d4) {
      int sl = d4 ^ swz;
      float4 wir = wi4[(lane << 4) + sl];
      float4 wiz = wi4[((lane + 64) << 4) + sl];
      float4 win = wi4[((lane + 128) << 4) + sl];
      float4 whr = wh4[(lane << 4) + sl];
      float4 whz = wh4[((lane + 64) << 4) + sl];
      float4 whn = wh4[((lane + 128) << 4) + sl];
#pragma unroll
      for (int e = 0; e < GABLK; ++e) {
        float4 av = a4[e * 16 + d4];
        float4 hv = h4[e * 16 + d4];
        air[e] += wir.x*av.x + wir.y*av.y + wir.z*av.z + wir.w*av.w;
        aiz[e] += wiz.x*av.x + wiz.y*av.y + wiz.z*av.z + wiz.w*av.w;
        ain[e] += win.x*av.x + win.y*av.y + win.z*av.z + win.w*av.w;
        ahr[e] += whr.x*hv.x + whr.y*hv.y + whr.z*hv.z + whr.w*hv.w;
        ahz[e] += whz.x*hv.x + whz.y*hv.y + whz.z*hv.z + whz.w*hv.w;
        ahn[e] += whn.x*hv.x + whn.y*hv.y + whn.z*hv.z + whn.w*hv.w;
      }
    }
#pragma unroll
    for (int e = 0; e < GABLK; ++e) {
      float r = sigmoidf_((air[e] + bir) + (ahr[e] + bhr));
      float z = sigmoidf_((aiz[e] + biz) + (ahz[e] + bhz));
      float nn = tanhf((ain[e] + bin_) + r * (ahn[e] + bhn));
      float hold = act_s[wv][1][e][lane];
      h[(ag + e) * 64 + lane] = (1.0f - z) * nn + z * hold;
    }
    __syncthreads();
  }
}

// ============ qkv projection + valid mask ============
#define QABLK 4
__global__ __launch_bounds__(256, 1) void k_qkv(
    const float* __restrict__ h, const float* __restrict__ w,
    const float* __restrict__ b, float* __restrict__ qkv,
    int* __restrict__ valid) {
  __shared__ __align__(16) float w_s[192 * 64];
  __shared__ __align__(16) float x_s[4][QABLK][64];
  const int tid = threadIdx.x, lane = tid & 63, wv = tid >> 6;
  for (int idx = tid; idx < 192 * 64; idx += 256) {
    int r = idx >> 6, d = idx & 63;
    w_s[(r << 6) + ((((d >> 2) ^ (r & 7)) << 2) | (d & 3))] = w[idx];
  }
  __syncthreads();
  const float4* w4 = reinterpret_cast<const float4*>(w_s);
  const float bq = b[lane], bk = b[64 + lane], bv_ = b[128 + lane];
  const int swz = lane & 7;
  const int gw = blockIdx.x * 4 + wv;
  const int stride = gridDim.x * 4 * QABLK;
  for (int ag = gw * QABLK; ag < NA; ag += stride) {
#pragma unroll
    for (int e = 0; e < QABLK; ++e) x_s[wv][e][lane] = h[(ag + e) * 64 + lane];
    __syncthreads();
    const float4* x4 = reinterpret_cast<const float4*>(&x_s[wv][0][0]);
    float aq[QABLK] = {0,0,0,0}, ak[QABLK] = {0,0,0,0}, av_[QABLK] = {0,0,0,0};
    int nz[QABLK] = {0,0,0,0};
#pragma unroll
    for (int d4 = 0; d4 < 16; ++d4) {
      int sl = d4 ^ swz;
      float4 wq = w4[(lane << 4) + sl];
      float4 wk = w4[((lane + 64) << 4) + sl];
      float4 wvv = w4[((lane + 128) << 4) + sl];
#pragma unroll
      for (int e = 0; e < QABLK; ++e) {
        float4 xv = x4[e * 16 + d4];
        aq[e] += wq.x*xv.x + wq.y*xv.y + wq.z*xv.z + wq.w*xv.w;
        ak[e] += wk.x*xv.x + wk.y*xv.y + wk.z*xv.z + wk.w*xv.w;
        av_[e] += wvv.x*xv.x + wvv.y*xv.y + wvv.z*xv.z + wvv.w*xv.w;
        nz[e] |= (int)(xv.x != 0.f) | (int)(xv.y != 0.f) | (int)(xv.z != 0.f) | (int)(xv.w != 0.f);
      }
    }
#pragma unroll
    for (int e = 0; e < QABLK; ++e) {
      qkv[(ag + e) * 192 + lane] = aq[e] + bq;
      qkv[(ag + e) * 192 + 64 + lane] = ak[e] + bk;
      qkv[(ag + e) * 192 + 128 + lane] = av_[e] + bv_;
      if (lane == 0) valid[ag + e] = nz[e];
    }
    __syncthreads();
  }
}

// ============ attention: one wave per (molecule, head), online softmax ============
__global__ void k_attn(const float* __restrict__ qkv, const int* __restrict__ valid,
                       float* __restrict__ ao) {
  const int b = blockIdx.x >> 3, hh = blockIdx.x & 7;
  __shared__ float k_s[64][8];
  __shared__ float v_s[64][8];
  __shared__ int vd_s[64];
  const int lane = threadIdx.x;
  const int rowbase = (b * 64 + lane) * 192;
#pragma unroll
  for (int j = 0; j < 8; ++j) {
    k_s[lane][j] = qkv[rowbase + 64 + hh * 8 + j];
    v_s[lane][j] = qkv[rowbase + 128 + hh * 8 + j];
  }
  vd_s[lane] = valid[b * 64 + lane];
  __syncthreads();
  float q[8];
#pragma unroll
  for (int j = 0; j < 8; ++j) q[j] = qkv[rowbase + hh * 8 + j];
  float m = -3.0e38f, l = 0.f, o[8] = {0,0,0,0,0,0,0,0};
  for (int t = 0; t < 64; ++t) {
    float s = 0.f;
#pragma unroll
    for (int j = 0; j < 8; ++j) s += q[j] * k_s[t][j];
    s *= 0.35355339059327373f;
    s = vd_s[t] ? s : -1.0e9f;
    float mn = fmaxf(m, s);
    float c = expf(m - mn);
    float p = expf(s - mn);
    l = l * c + p;
#pragma unroll
    for (int j = 0; j < 8; ++j) o[j] = o[j] * c + p * v_s[t][j];
    m = mn;
  }
  const float inv = 1.0f / l;
  const int obase = (b * 64 + lane) * 64 + hh * 8;
#pragma unroll
  for (int j = 0; j < 8; ++j) ao[obase + j] = o[j] * inv;
}

// ============ out_proj + residual + LN1 ============
#define OABLK 4
__global__ __launch_bounds__(256, 1) void k_out_ln1(
    const float* __restrict__ x, const float* __restrict__ ao,
    const float* __restrict__ w, const float* __restrict__ bias,
    const float* __restrict__ g, const float* __restrict__ bb,
    float* __restrict__ y1) {
  __shared__ __align__(16) float w_s[64 * 64];
  __shared__ __align__(16) float a_s[4][OABLK][64];
  const int tid = threadIdx.x, lane = tid & 63, wv = tid >> 6;
  for (int idx = tid; idx < 64 * 64; idx += 256) {
    int r = idx >> 6, d = idx & 63;
    w_s[(r << 6) + ((((d >> 2) ^ (r & 7)) << 2) | (d & 3))] = w[idx];
  }
  __syncthreads();
  const float4* w4 = reinterpret_cast<const float4*>(w_s);
  const float bo = bias[lane], gg = g[lane], bbb = bb[lane];
  const int swz = lane & 7;
  const int gw = blockIdx.x * 4 + wv;
  const int stride = gridDim.x * 4 * OABLK;
  for (int ag = gw * OABLK; ag < NA; ag += stride) {
#pragma unroll
    for (int e = 0; e < OABLK; ++e) a_s[wv][e][lane] = ao[(ag + e) * 64 + lane];
    __syncthreads();
    const float4* a4 = reinterpret_cast<const float4*>(&a_s[wv][0][0]);
    float acc[OABLK] = {0,0,0,0};
#pragma unroll
    for (int d4 = 0; d4 < 16; ++d4) {
      int sl = d4 ^ swz;
      float4 wr = w4[(lane << 4) + sl];
#pragma unroll
      for (int e = 0; e < OABLK; ++e) {
        float4 av = a4[e * 16 + d4];
        acc[e] += wr.x*av.x + wr.y*av.y + wr.z*av.z + wr.w*av.w;
      }
    }
#pragma unroll
    for (int e = 0; e < OABLK; ++e) {
      float val = acc[e] + bo + x[(ag + e) * 64 + lane];
      float s1 = val, s2 = val * val;
#pragma unroll
      for (int mm = 1; mm < 64; mm <<= 1) {
        s1 += __shfl_xor(s1, mm, 64);
        s2 += __shfl_xor(s2, mm, 64);
      }
      float mu = s1 * 0.015625f;
      float var = s2 * 0.015625f - mu * mu;
      y1[(ag + e) * 64 + lane] = (val - mu) * rsqrtf(var + 1e-5f) * gg + bbb;
    }
    __syncthreads();
  }
}

// ============ FFN (512 hidden) + residual + LN2 ============
#define FABLK 4
__global__ __launch_bounds__(256, 1) void k_ffn(
    const float* __restrict__ y1, const float* __restrict__ w1,
    const float* __restrict__ b1, const float* __restrict__ w2,
    const float* __restrict__ b2, const float* __restrict__ g,
    const float* __restrict__ bb, float* __restrict__ y2) {
  __shared__ __align__(16) float hbuf[4][FABLK][512];
  __shared__ __align__(16) float y1_s[4][FABLK][64];
  const int tid = threadIdx.x, lane = tid & 63, wv = tid >> 6;
  float bb1[8];
#pragma unroll
  for (int cc = 0; cc < 8; ++cc) bb1[cc] = b1[cc * 64 + lane];
  const float b2v = b2[lane], gg = g[lane], bbb = bb[lane];
  const int gw = blockIdx.x * 4 + wv;
  const int stride = gridDim.x * 4 * FABLK;
  for (int ag = gw * FABLK; ag < NA; ag += stride) {
#pragma unroll
    for (int e = 0; e < FABLK; ++e) y1_s[wv][e][lane] = y1[(ag + e) * 64 + lane];
    __syncthreads();
    float hv[FABLK][8];
#pragma unroll
    for (int e = 0; e < FABLK; ++e)
#pragma unroll
      for (int cc = 0; cc < 8; ++cc) hv[e][cc] = bb1[cc];
    for (int d = 0; d < 64; ++d) {
      float w1v[8];
#pragma unroll
      for (int cc = 0; cc < 8; ++cc) w1v[cc] = w1[d * 512 + cc * 64 + lane];
#pragma unroll
      for (int e = 0; e < FABLK; ++e) {
        float yv = y1_s[wv][e][d];
#pragma unroll
        for (int cc = 0; cc < 8; ++cc) hv[e][cc] += yv * w1v[cc];
      }
    }
#pragma unroll
    for (int e = 0; e < FABLK; ++e)
#pragma unroll
      for (int cc = 0; cc < 8; ++cc)
        hbuf[wv][e][cc * 64 + lane] = fmaxf(hv[e][cc], 0.f);
    __syncthreads();
    float acc[FABLK] = {0,0,0,0};
    const float4* hb4 = reinterpret_cast<const float4*>(&hbuf[wv][0][0]);
    for (int c4 = 0; c4 < 128; ++c4) {
      float w2v[4];
#pragma unroll
      for (int qq = 0; qq < 4; ++qq) w2v[qq] = w2[(c4 * 4 + qq) * 64 + lane];
#pragma unroll
      for (int e = 0; e < FABLK; ++e) {
        float4 hq = hb4[e * 128 + c4];
        acc[e] += hq.x * w2v[0] + hq.y * w2v[1] + hq.z * w2v[2] + hq.w * w2v[3];
      }
    }
#pragma unroll
    for (int e = 0; e < FABLK; ++e) {
      float val = y1_s[wv][e][lane] + acc[e] + b2v;
      float s1 = val, s2 = val * val;
#pragma unroll
      for (int mm = 1; mm < 64; mm <<= 1) {
        s1 += __shfl_xor(s1, mm, 64);
        s2 += __shfl_xor(s2, mm, 64);
      }
      float mu = s1 * 0.015625f;
      float var = s2 * 0.015625f - mu * mu;
      y2[(ag + e) * 64 + lane] = (val - mu) * rsqrtf(var + 1e-5f) * gg + bbb;
    }
    __syncthreads();
  }
}

// ============ mean-pool over tokens ============
__global__ void k_pool(const float* __restrict__ y2, float* __restrict__ pooled) {
  const int b = blockIdx.x, lane = threadIdx.x;
  float s = 0.f;
  for (int t = 0; t < 64; ++t) s += y2[(b * 64 + t) * 64 + lane];
  pooled[b * 64 + lane] = s * 0.015625f;
}

// ============ readout head ============
__global__ __launch_bounds__(256) void k_head(
    const float* __restrict__ pooled, const float* __restrict__ d1w,
    const float* __restrict__ d1b, const float* __restrict__ d2w,
    const float* __restrict__ d2b, float* __restrict__ out) {
  const int b = blockIdx.x;
  __shared__ float p_s[64];
  __shared__ float red_s[4];
  const int tid = threadIdx.x;
  if (tid < 64) p_s[tid] = pooled[b * 64 + tid];
  __syncthreads();
  float acc = 0.f;
#pragma unroll
  for (int rep = 0; rep < 2; ++rep) {
    int c = rep * 256 + tid;
    float hvv = d1b[c];
    for (int d = 0; d < 64; ++d) hvv += p_s[d] * d1w[d * 512 + c];
    acc += fmaxf(hvv, 0.f) * d2w[c];
  }
#pragma unroll
  for (int mm = 1; mm < 64; mm <<= 1) acc += __shfl_xor(acc, mm, 64);
  if ((tid & 63) == 0) red_s[tid >> 6] = acc;
  __syncthreads();
  if (tid == 0) {
    float t = red_s[0] + red_s[1] + red_s[2] + red_s[3] + d2b[0];
    out[b] = 1.0f / (1.0f + expf(-t));
  }
}

extern "C" void kernel_launch(void* const* d_in, const int* in_sizes, int n_in,
                              void* d_out, int out_size, void* d_ws, size_t ws_size,
                              hipStream_t stream) {
  (void)in_sizes; (void)n_in; (void)out_size; (void)ws_size;
  const float* af   = (const float*)d_in[0];
  const float* bfeat= (const float*)d_in[1];
  const int*   pairs= (const int*)d_in[2];
  // d_in[3] = molecule_indicator (identity layout; unused)
  const float* kern = (const float*)d_in[4];
  const float* kbias= (const float*)d_in[5];
  const float* wih  = (const float*)d_in[6];
  const float* whh  = (const float*)d_in[7];
  const float* bih  = (const float*)d_in[8];
  const float* bhh  = (const float*)d_in[9];
  const float* ipw  = (const float*)d_in[10];
  const float* ipb  = (const float*)d_in[11];
  const float* opw  = (const float*)d_in[12];
  const float* opb  = (const float*)d_in[13];
  const float* fw1  = (const float*)d_in[14];
  const float* fb1  = (const float*)d_in[15];
  const float* fw2  = (const float*)d_in[16];
  const float* fb2  = (const float*)d_in[17];
  const float* l1g  = (const float*)d_in[18];
  const float* l1b  = (const float*)d_in[19];
  const float* l2g  = (const float*)d_in[20];
  const float* l2b  = (const float*)d_in[21];
  const float* d1w  = (const float*)d_in[22];
  const float* d1b  = (const float*)d_in[23];
  const float* d2w  = (const float*)d_in[24];
  const float* d2b  = (const float*)d_in[25];
  float* out = (float*)d_out;

  // workspace layout (floats): total ~8.42M floats (~34 MB)
  float* ws = (float*)d_ws;
  float* h      = ws;
  float* agg    = h + (size_t)NA * 64;
  float* qkv    = agg + (size_t)NA * 64;
  float* ao     = qkv + (size_t)NA * 192;
  float* y1     = ao + (size_t)NA * 64;
  float* y2     = y1 + (size_t)NA * 64;
  float* pooled = y2 + (size_t)NA * 64;
  int*   valid  = (int*)(pooled + 256 * 64);

  k_init_h<<<NA * 64 / 256, 256, 0, stream>>>(af, h);
  for (int s = 0; s < 4; ++s) {
    hipMemsetAsync(agg, 0, (size_t)NA * 64 * sizeof(float), stream);
    k_edge<<<256, 256, 0, stream>>>(bfeat, pairs, kern, kbias, h, agg);
    k_gru<<<256, 256, 0, stream>>>(agg, wih, whh, bih, bhh, h);
  }
  k_qkv<<<256, 256, 0, stream>>>(h, ipw, ipb, qkv, valid);
  k_attn<<<2048, 64, 0, stream>>>(qkv, valid, ao);
  k_out_ln1<<<256, 256, 0, stream>>>(h, ao, opw, opb, l1g, l1b, y1);
  k_ffn<<<256, 256, 0, stream>>>(y1, fw1, fb1, fw2, fb2, l2g, l2b, y2);
  k_pool<<<256, 64, 0, stream>>>(y2, pooled);
  k_head<<<256, 256, 0, stream>>>(pooled, d1w, d1b, d2w, d2b, out);
}

// Round 2
// 1005.766 us; speedup vs baseline: 1.9600x; 1.9600x over previous
//
#include <hip/hip_runtime.h>
#include <math.h>

#define NA 16384
#define NE 65536
#define AD 29

__device__ __forceinline__ float sigmoidf_(float x) { return 1.0f / (1.0f + expf(-x)); }

// ============ init h: pad atom features 29 -> 64 ============
__global__ void k_init_h(const float* __restrict__ af, float* __restrict__ h) {
  int idx = blockIdx.x * 256 + threadIdx.x;
  if (idx >= NA * 64) return;
  int a = idx >> 6, d = idx & 63;
  h[idx] = (d < AD) ? af[a * AD + d] : 0.0f;
}

// ============ edge message + scatter-add ============
// msg[e,i] = sum_j (sum_k bf[e,k]*K[k][i*64+j] + bias[i*64+j]) * h[dst_e][j]
// kernel+bias (144 KB) staged in LDS, XOR-swizzled so lane-strided b128 reads
// are conflict-free. 512 threads = 8 waves -> 2 waves/SIMD. Unroll capped to
// keep live ranges under the 256-VGPR cliff (round-1 spill lesson).
#define EBLK 4
__global__ __launch_bounds__(512, 1) void k_edge(
    const float* __restrict__ bf, const int* __restrict__ pairs,
    const float* __restrict__ kern, const float* __restrict__ kbias,
    const float* __restrict__ h, float* __restrict__ agg) {
  __shared__ __align__(16) float ker_s[9 * 4096];      // 8 kernel slabs + bias slab
  __shared__ __align__(16) float nbr_s[8][EBLK][64];
  const int tid = threadIdx.x;
  const int lane = tid & 63;
  const int wv = tid >> 6;

  for (int idx = tid; idx < 9 * 4096; idx += 512) {
    int k = idx >> 12;
    int rem = idx & 4095;
    int i = rem >> 6, j = rem & 63;
    float v = (k < 8) ? kern[idx] : kbias[rem];
    ker_s[(k << 12) + (i << 6) + ((((j >> 2) ^ (i & 7)) << 2) | (j & 3))] = v;
  }
  __syncthreads();

  const float4* ks4 = reinterpret_cast<const float4*>(ker_s);
  const int swz = lane & 7;
  const int base = lane << 4;           // lane*16 float4s (row i = lane)
  const int gw = blockIdx.x * 8 + wv;
  const int stride = gridDim.x * 8 * EBLK;

  for (int eg = gw * EBLK; eg < NE; eg += stride) {
    float bval = 0.0f;
    if (lane < 8 * EBLK) bval = bf[(eg + (lane >> 3)) * 8 + (lane & 7)];
    float bfs[EBLK][8];
#pragma unroll
    for (int e = 0; e < EBLK; ++e)
#pragma unroll
      for (int k = 0; k < 8; ++k) bfs[e][k] = __shfl(bval, e * 8 + k, 64);

    int srcs[EBLK];
#pragma unroll
    for (int e = 0; e < EBLK; ++e) {
      int2 p = reinterpret_cast<const int2*>(pairs)[eg + e];
      srcs[e] = p.x;
      nbr_s[wv][e][lane] = h[p.y * 64 + lane];
    }
    __syncthreads();

    const float4* nb4 = reinterpret_cast<const float4*>(&nbr_s[wv][0][0]);
    float msg[EBLK] = {0.f, 0.f, 0.f, 0.f};
#pragma unroll 2
    for (int j4 = 0; j4 < 16; ++j4) {
      int slot = j4 ^ swz;
      float4 kv[8];
#pragma unroll
      for (int k = 0; k < 8; ++k) kv[k] = ks4[(k << 10) + base + slot];
      float4 bv = ks4[(8 << 10) + base + slot];
#pragma unroll
      for (int e = 0; e < EBLK; ++e) {
        float4 nb = nb4[e * 16 + j4];
        float4 m = bv;
#pragma unroll
        for (int k = 0; k < 8; ++k) {
          m.x = fmaf(bfs[e][k], kv[k].x, m.x);
          m.y = fmaf(bfs[e][k], kv[k].y, m.y);
          m.z = fmaf(bfs[e][k], kv[k].z, m.z);
          m.w = fmaf(bfs[e][k], kv[k].w, m.w);
        }
        msg[e] += m.x * nb.x + m.y * nb.y + m.z * nb.z + m.w * nb.w;
      }
    }
#pragma unroll
    for (int e = 0; e < EBLK; ++e) atomicAdd(&agg[srcs[e] * 64 + lane], msg[e]);
    __syncthreads();
  }
}

// ============ GRU cell (per atom) ============
// 512 threads = 8 waves -> 2 waves/SIMD at 112 KB LDS. Unroll capped at 2 so
// live float4 ranges stay ~150 VGPR (round-1: full unroll hit the 256-VGPR
// cap and spilled ~1 GB of scratch traffic to HBM).
#define GABLK 4
__global__ __launch_bounds__(512, 1) void k_gru(
    const float* __restrict__ agg, const float* __restrict__ wih,
    const float* __restrict__ whh, const float* __restrict__ bih,
    const float* __restrict__ bhh, float* __restrict__ h) {
  __shared__ __align__(16) float wih_s[192 * 64];
  __shared__ __align__(16) float whh_s[192 * 64];
  __shared__ __align__(16) float act_s[8][2][GABLK][64];
  const int tid = threadIdx.x, lane = tid & 63, wv = tid >> 6;

  for (int idx = tid; idx < 192 * 64; idx += 512) {
    int r = idx >> 6, d = idx & 63;
    int pos = (r << 6) + ((((d >> 2) ^ (r & 7)) << 2) | (d & 3));
    wih_s[pos] = wih[idx];
    whh_s[pos] = whh[idx];
  }
  __syncthreads();

  const float4* wi4 = reinterpret_cast<const float4*>(wih_s);
  const float4* wh4 = reinterpret_cast<const float4*>(whh_s);
  const float bir = bih[lane], biz = bih[64 + lane], bin_ = bih[128 + lane];
  const float bhr = bhh[lane], bhz = bhh[64 + lane], bhn = bhh[128 + lane];
  const int swz = lane & 7;
  const int gw = blockIdx.x * 8 + wv;
  const int stride = gridDim.x * 8 * GABLK;

  for (int ag = gw * GABLK; ag < NA; ag += stride) {
#pragma unroll
    for (int e = 0; e < GABLK; ++e) {
      act_s[wv][0][e][lane] = agg[(ag + e) * 64 + lane];
      act_s[wv][1][e][lane] = h[(ag + e) * 64 + lane];
    }
    __syncthreads();
    const float4* a4 = reinterpret_cast<const float4*>(&act_s[wv][0][0][0]);
    const float4* h4 = reinterpret_cast<const float4*>(&act_s[wv][1][0][0]);
    float air[GABLK] = {0,0,0,0}, aiz[GABLK] = {0,0,0,0}, ain[GABLK] = {0,0,0,0};
    float ahr[GABLK] = {0,0,0,0}, ahz[GABLK] = {0,0,0,0}, ahn[GABLK] = {0,0,0,0};
#pragma unroll 2
    for (int d4 = 0; d4 < 16; ++d4) {
      int sl = d4 ^ swz;
      float4 wir = wi4[(lane << 4) + sl];
      float4 wiz = wi4[((lane + 64) << 4) + sl];
      float4 win = wi4[((lane + 128) << 4) + sl];
      float4 whr = wh4[(lane << 4) + sl];
      float4 whz = wh4[((lane + 64) << 4) + sl];
      float4 whn = wh4[((lane + 128) << 4) + sl];
#pragma unroll
      for (int e = 0; e < GABLK; ++e) {
        float4 av = a4[e * 16 + d4];
        float4 hv = h4[e * 16 + d4];
        air[e] += wir.x*av.x + wir.y*av.y + wir.z*av.z + wir.w*av.w;
        aiz[e] += wiz.x*av.x + wiz.y*av.y + wiz.z*av.z + wiz.w*av.w;
        ain[e] += win.x*av.x + win.y*av.y + win.z*av.z + win.w*av.w;
        ahr[e] += whr.x*hv.x + whr.y*hv.y + whr.z*hv.z + whr.w*hv.w;
        ahz[e] += whz.x*hv.x + whz.y*hv.y + whz.z*hv.z + whz.w*hv.w;
        ahn[e] += whn.x*hv.x + whn.y*hv.y + whn.z*hv.z + whn.w*hv.w;
      }
    }
#pragma unroll
    for (int e = 0; e < GABLK; ++e) {
      float r = sigmoidf_((air[e] + bir) + (ahr[e] + bhr));
      float z = sigmoidf_((aiz[e] + biz) + (ahz[e] + bhz));
      float nn = tanhf((ain[e] + bin_) + r * (ahn[e] + bhn));
      float hold = act_s[wv][1][e][lane];
      h[(ag + e) * 64 + lane] = (1.0f - z) * nn + z * hold;
    }
    __syncthreads();
  }
}

// ============ qkv projection + valid mask ============
#define QABLK 4
__global__ __launch_bounds__(256, 1) void k_qkv(
    const float* __restrict__ h, const float* __restrict__ w,
    const float* __restrict__ b, float* __restrict__ qkv,
    int* __restrict__ valid) {
  __shared__ __align__(16) float w_s[192 * 64];
  __shared__ __align__(16) float x_s[4][QABLK][64];
  const int tid = threadIdx.x, lane = tid & 63, wv = tid >> 6;
  for (int idx = tid; idx < 192 * 64; idx += 256) {
    int r = idx >> 6, d = idx & 63;
    w_s[(r << 6) + ((((d >> 2) ^ (r & 7)) << 2) | (d & 3))] = w[idx];
  }
  __syncthreads();
  const float4* w4 = reinterpret_cast<const float4*>(w_s);
  const float bq = b[lane], bk = b[64 + lane], bv_ = b[128 + lane];
  const int swz = lane & 7;
  const int gw = blockIdx.x * 4 + wv;
  const int stride = gridDim.x * 4 * QABLK;
  for (int ag = gw * QABLK; ag < NA; ag += stride) {
#pragma unroll
    for (int e = 0; e < QABLK; ++e) x_s[wv][e][lane] = h[(ag + e) * 64 + lane];
    __syncthreads();
    const float4* x4 = reinterpret_cast<const float4*>(&x_s[wv][0][0]);
    float aq[QABLK] = {0,0,0,0}, ak[QABLK] = {0,0,0,0}, av_[QABLK] = {0,0,0,0};
    int nz[QABLK] = {0,0,0,0};
#pragma unroll 4
    for (int d4 = 0; d4 < 16; ++d4) {
      int sl = d4 ^ swz;
      float4 wq = w4[(lane << 4) + sl];
      float4 wk = w4[((lane + 64) << 4) + sl];
      float4 wvv = w4[((lane + 128) << 4) + sl];
#pragma unroll
      for (int e = 0; e < QABLK; ++e) {
        float4 xv = x4[e * 16 + d4];
        aq[e] += wq.x*xv.x + wq.y*xv.y + wq.z*xv.z + wq.w*xv.w;
        ak[e] += wk.x*xv.x + wk.y*xv.y + wk.z*xv.z + wk.w*xv.w;
        av_[e] += wvv.x*xv.x + wvv.y*xv.y + wvv.z*xv.z + wvv.w*xv.w;
        nz[e] |= (int)(xv.x != 0.f) | (int)(xv.y != 0.f) | (int)(xv.z != 0.f) | (int)(xv.w != 0.f);
      }
    }
#pragma unroll
    for (int e = 0; e < QABLK; ++e) {
      qkv[(ag + e) * 192 + lane] = aq[e] + bq;
      qkv[(ag + e) * 192 + 64 + lane] = ak[e] + bk;
      qkv[(ag + e) * 192 + 128 + lane] = av_[e] + bv_;
      if (lane == 0) valid[ag + e] = nz[e];
    }
    __syncthreads();
  }
}

// ============ attention: one wave per (molecule, head), online softmax ============
__global__ void k_attn(const float* __restrict__ qkv, const int* __restrict__ valid,
                       float* __restrict__ ao) {
  const int b = blockIdx.x >> 3, hh = blockIdx.x & 7;
  __shared__ float k_s[64][8];
  __shared__ float v_s[64][8];
  __shared__ int vd_s[64];
  const int lane = threadIdx.x;
  const int rowbase = (b * 64 + lane) * 192;
#pragma unroll
  for (int j = 0; j < 8; ++j) {
    k_s[lane][j] = qkv[rowbase + 64 + hh * 8 + j];
    v_s[lane][j] = qkv[rowbase + 128 + hh * 8 + j];
  }
  vd_s[lane] = valid[b * 64 + lane];
  __syncthreads();
  float q[8];
#pragma unroll
  for (int j = 0; j < 8; ++j) q[j] = qkv[rowbase + hh * 8 + j];
  float m = -3.0e38f, l = 0.f, o[8] = {0,0,0,0,0,0,0,0};
  for (int t = 0; t < 64; ++t) {
    float s = 0.f;
#pragma unroll
    for (int j = 0; j < 8; ++j) s += q[j] * k_s[t][j];
    s *= 0.35355339059327373f;
    s = vd_s[t] ? s : -1.0e9f;
    float mn = fmaxf(m, s);
    float c = expf(m - mn);
    float p = expf(s - mn);
    l = l * c + p;
#pragma unroll
    for (int j = 0; j < 8; ++j) o[j] = o[j] * c + p * v_s[t][j];
    m = mn;
  }
  const float inv = 1.0f / l;
  const int obase = (b * 64 + lane) * 64 + hh * 8;
#pragma unroll
  for (int j = 0; j < 8; ++j) ao[obase + j] = o[j] * inv;
}

// ============ out_proj + residual + LN1 ============
#define OABLK 4
__global__ __launch_bounds__(256, 1) void k_out_ln1(
    const float* __restrict__ x, const float* __restrict__ ao,
    const float* __restrict__ w, const float* __restrict__ bias,
    const float* __restrict__ g, const float* __restrict__ bb,
    float* __restrict__ y1) {
  __shared__ __align__(16) float w_s[64 * 64];
  __shared__ __align__(16) float a_s[4][OABLK][64];
  const int tid = threadIdx.x, lane = tid & 63, wv = tid >> 6;
  for (int idx = tid; idx < 64 * 64; idx += 256) {
    int r = idx >> 6, d = idx & 63;
    w_s[(r << 6) + ((((d >> 2) ^ (r & 7)) << 2) | (d & 3))] = w[idx];
  }
  __syncthreads();
  const float4* w4 = reinterpret_cast<const float4*>(w_s);
  const float bo = bias[lane], gg = g[lane], bbb = bb[lane];
  const int swz = lane & 7;
  const int gw = blockIdx.x * 4 + wv;
  const int stride = gridDim.x * 4 * OABLK;
  for (int ag = gw * OABLK; ag < NA; ag += stride) {
#pragma unroll
    for (int e = 0; e < OABLK; ++e) a_s[wv][e][lane] = ao[(ag + e) * 64 + lane];
    __syncthreads();
    const float4* a4 = reinterpret_cast<const float4*>(&a_s[wv][0][0]);
    float acc[OABLK] = {0,0,0,0};
#pragma unroll 4
    for (int d4 = 0; d4 < 16; ++d4) {
      int sl = d4 ^ swz;
      float4 wr = w4[(lane << 4) + sl];
#pragma unroll
      for (int e = 0; e < OABLK; ++e) {
        float4 av = a4[e * 16 + d4];
        acc[e] += wr.x*av.x + wr.y*av.y + wr.z*av.z + wr.w*av.w;
      }
    }
#pragma unroll
    for (int e = 0; e < OABLK; ++e) {
      float val = acc[e] + bo + x[(ag + e) * 64 + lane];
      float s1 = val, s2 = val * val;
#pragma unroll
      for (int mm = 1; mm < 64; mm <<= 1) {
        s1 += __shfl_xor(s1, mm, 64);
        s2 += __shfl_xor(s2, mm, 64);
      }
      float mu = s1 * 0.015625f;
      float var = s2 * 0.015625f - mu * mu;
      y1[(ag + e) * 64 + lane] = (val - mu) * rsqrtf(var + 1e-5f) * gg + bbb;
    }
    __syncthreads();
  }
}

// ============ FFN (512 hidden) + residual + LN2 ============
#define FABLK 4
__global__ __launch_bounds__(256, 1) void k_ffn(
    const float* __restrict__ y1, const float* __restrict__ w1,
    const float* __restrict__ b1, const float* __restrict__ w2,
    const float* __restrict__ b2, const float* __restrict__ g,
    const float* __restrict__ bb, float* __restrict__ y2) {
  __shared__ __align__(16) float hbuf[4][FABLK][512];
  __shared__ __align__(16) float y1_s[4][FABLK][64];
  const int tid = threadIdx.x, lane = tid & 63, wv = tid >> 6;
  float bb1[8];
#pragma unroll
  for (int cc = 0; cc < 8; ++cc) bb1[cc] = b1[cc * 64 + lane];
  const float b2v = b2[lane], gg = g[lane], bbb = bb[lane];
  const int gw = blockIdx.x * 4 + wv;
  const int stride = gridDim.x * 4 * FABLK;
  for (int ag = gw * FABLK; ag < NA; ag += stride) {
#pragma unroll
    for (int e = 0; e < FABLK; ++e) y1_s[wv][e][lane] = y1[(ag + e) * 64 + lane];
    __syncthreads();
    float hv[FABLK][8];
#pragma unroll
    for (int e = 0; e < FABLK; ++e)
#pragma unroll
      for (int cc = 0; cc < 8; ++cc) hv[e][cc] = bb1[cc];
#pragma unroll 4
    for (int d = 0; d < 64; ++d) {
      float w1v[8];
#pragma unroll
      for (int cc = 0; cc < 8; ++cc) w1v[cc] = w1[d * 512 + cc * 64 + lane];
#pragma unroll
      for (int e = 0; e < FABLK; ++e) {
        float yv = y1_s[wv][e][d];
#pragma unroll
        for (int cc = 0; cc < 8; ++cc) hv[e][cc] += yv * w1v[cc];
      }
    }
#pragma unroll
    for (int e = 0; e < FABLK; ++e)
#pragma unroll
      for (int cc = 0; cc < 8; ++cc)
        hbuf[wv][e][cc * 64 + lane] = fmaxf(hv[e][cc], 0.f);
    __syncthreads();
    float acc[FABLK] = {0,0,0,0};
    const float4* hb4 = reinterpret_cast<const float4*>(&hbuf[wv][0][0]);
#pragma unroll 4
    for (int c4 = 0; c4 < 128; ++c4) {
      float w2v[4];
#pragma unroll
      for (int qq = 0; qq < 4; ++qq) w2v[qq] = w2[(c4 * 4 + qq) * 64 + lane];
#pragma unroll
      for (int e = 0; e < FABLK; ++e) {
        float4 hq = hb4[e * 128 + c4];
        acc[e] += hq.x * w2v[0] + hq.y * w2v[1] + hq.z * w2v[2] + hq.w * w2v[3];
      }
    }
#pragma unroll
    for (int e = 0; e < FABLK; ++e) {
      float val = y1_s[wv][e][lane] + acc[e] + b2v;
      float s1 = val, s2 = val * val;
#pragma unroll
      for (int mm = 1; mm < 64; mm <<= 1) {
        s1 += __shfl_xor(s1, mm, 64);
        s2 += __shfl_xor(s2, mm, 64);
      }
      float mu = s1 * 0.015625f;
      float var = s2 * 0.015625f - mu * mu;
      y2[(ag + e) * 64 + lane] = (val - mu) * rsqrtf(var + 1e-5f) * gg + bbb;
    }
    __syncthreads();
  }
}

// ============ mean-pool over tokens ============
__global__ void k_pool(const float* __restrict__ y2, float* __restrict__ pooled) {
  const int b = blockIdx.x, lane = threadIdx.x;
  float s = 0.f;
  for (int t = 0; t < 64; ++t) s += y2[(b * 64 + t) * 64 + lane];
  pooled[b * 64 + lane] = s * 0.015625f;
}

// ============ readout head ============
__global__ __launch_bounds__(256) void k_head(
    const float* __restrict__ pooled, const float* __restrict__ d1w,
    const float* __restrict__ d1b, const float* __restrict__ d2w,
    const float* __restrict__ d2b, float* __restrict__ out) {
  const int b = blockIdx.x;
  __shared__ float p_s[64];
  __shared__ float red_s[4];
  const int tid = threadIdx.x;
  if (tid < 64) p_s[tid] = pooled[b * 64 + tid];
  __syncthreads();
  float acc = 0.f;
#pragma unroll
  for (int rep = 0; rep < 2; ++rep) {
    int c = rep * 256 + tid;
    float hvv = d1b[c];
    for (int d = 0; d < 64; ++d) hvv += p_s[d] * d1w[d * 512 + c];
    acc += fmaxf(hvv, 0.f) * d2w[c];
  }
#pragma unroll
  for (int mm = 1; mm < 64; mm <<= 1) acc += __shfl_xor(acc, mm, 64);
  if ((tid & 63) == 0) red_s[tid >> 6] = acc;
  __syncthreads();
  if (tid == 0) {
    float t = red_s[0] + red_s[1] + red_s[2] + red_s[3] + d2b[0];
    out[b] = 1.0f / (1.0f + expf(-t));
  }
}

extern "C" void kernel_launch(void* const* d_in, const int* in_sizes, int n_in,
                              void* d_out, int out_size, void* d_ws, size_t ws_size,
                              hipStream_t stream) {
  (void)in_sizes; (void)n_in; (void)out_size; (void)ws_size;
  const float* af   = (const float*)d_in[0];
  const float* bfeat= (const float*)d_in[1];
  const int*   pairs= (const int*)d_in[2];
  // d_in[3] = molecule_indicator (identity layout; unused)
  const float* kern = (const float*)d_in[4];
  const float* kbias= (const float*)d_in[5];
  const float* wih  = (const float*)d_in[6];
  const float* whh  = (const float*)d_in[7];
  const float* bih  = (const float*)d_in[8];
  const float* bhh  = (const float*)d_in[9];
  const float* ipw  = (const float*)d_in[10];
  const float* ipb  = (const float*)d_in[11];
  const float* opw  = (const float*)d_in[12];
  const float* opb  = (const float*)d_in[13];
  const float* fw1  = (const float*)d_in[14];
  const float* fb1  = (const float*)d_in[15];
  const float* fw2  = (const float*)d_in[16];
  const float* fb2  = (const float*)d_in[17];
  const float* l1g  = (const float*)d_in[18];
  const float* l1b  = (const float*)d_in[19];
  const float* l2g  = (const float*)d_in[20];
  const float* l2b  = (const float*)d_in[21];
  const float* d1w  = (const float*)d_in[22];
  const float* d1b  = (const float*)d_in[23];
  const float* d2w  = (const float*)d_in[24];
  const float* d2b  = (const float*)d_in[25];
  float* out = (float*)d_out;

  // workspace layout (floats): total ~8.42M floats (~34 MB)
  float* ws = (float*)d_ws;
  float* h      = ws;
  float* agg    = h + (size_t)NA * 64;
  float* qkv    = agg + (size_t)NA * 64;
  float* ao     = qkv + (size_t)NA * 192;
  float* y1     = ao + (size_t)NA * 64;
  float* y2     = y1 + (size_t)NA * 64;
  float* pooled = y2 + (size_t)NA * 64;
  int*   valid  = (int*)(pooled + 256 * 64);

  k_init_h<<<NA * 64 / 256, 256, 0, stream>>>(af, h);
  for (int s = 0; s < 4; ++s) {
    hipMemsetAsync(agg, 0, (size_t)NA * 64 * sizeof(float), stream);
    k_edge<<<128, 512, 0, stream>>>(bfeat, pairs, kern, kbias, h, agg);
    k_gru<<<128, 512, 0, stream>>>(agg, wih, whh, bih, bhh, h);
  }
  k_qkv<<<256, 256, 0, stream>>>(h, ipw, ipb, qkv, valid);
  k_attn<<<2048, 64, 0, stream>>>(qkv, valid, ao);
  k_out_ln1<<<256, 256, 0, stream>>>(h, ao, opw, opb, l1g, l1b, y1);
  k_ffn<<<256, 256, 0, stream>>>(y1, fw1, fb1, fw2, fb2, l2g, l2b, y2);
  k_pool<<<256, 64, 0, stream>>>(y2, pooled);
  k_head<<<256, 256, 0, stream>>>(pooled, d1w, d1b, d2w, d2b, out);
}

// Round 3
// 656.523 us; speedup vs baseline: 3.0027x; 1.5320x over previous
//
#include <hip/hip_runtime.h>
#include <hip/hip_bf16.h>
#include <math.h>

#define NA 16384
#define NE 65536
#define AD 29

__device__ __forceinline__ float sigmoidf_(float x) { return 1.0f / (1.0f + expf(-x)); }

__device__ __forceinline__ float g_load(const float* p) { return *p; }
__device__ __forceinline__ float g_load(const __hip_bfloat16* p) { return __bfloat162float(*p); }
__device__ __forceinline__ void g_store(float* p, float v) { *p = v; }
__device__ __forceinline__ void g_store(__hip_bfloat16* p, float v) { *p = __float2bfloat16(v); }

// ============ init h: pad atom features 29 -> 64 ============
__global__ void k_init_h(const float* __restrict__ af, float* __restrict__ h) {
  int idx = blockIdx.x * 256 + threadIdx.x;
  if (idx >= NA * 64) return;
  int a = idx >> 6, d = idx & 63;
  h[idx] = (d < AD) ? af[a * AD + d] : 0.0f;
}

// ============ per-atom G precompute: G[a, k*64+i] = sum_j K[k][i*64+j]*h[a,j] ============
// (slab k=8 is the bias matrix). One [NA x 64] @ [64 x 576] GEMM = 1.2 GFLOP,
// replacing the 4.8 GFLOP per-edge matrix build. Weights (144 KB) in LDS,
// XOR-swizzled; lane owns 9 output rows (576/64); 4 atoms per wave.
#define GB_ABLK 4
template <typename GT>
__global__ __launch_bounds__(512, 1) void k_gemm_G(
    const float* __restrict__ h, const float* __restrict__ kern,
    const float* __restrict__ kbias, GT* __restrict__ G) {
  __shared__ __align__(16) float w_s[576 * 64];          // 144 KB
  __shared__ __align__(16) float h_s[8][GB_ABLK][64];    // 8 KB
  const int tid = threadIdx.x, lane = tid & 63, wv = tid >> 6;

  for (int idx = tid; idx < 576 * 64; idx += 512) {
    int c = idx >> 6, j = idx & 63;
    float v = (c < 512) ? kern[((c >> 6) << 12) + ((c & 63) << 6) + j]
                        : kbias[((c & 63) << 6) + j];
    w_s[(c << 6) + ((((j >> 2) ^ (c & 7)) << 2) | (j & 3))] = v;
  }
  __syncthreads();

  const float4* w4 = reinterpret_cast<const float4*>(w_s);
  const int swz = lane & 7;
  const int gw = blockIdx.x * 8 + wv;
  const int stride = gridDim.x * 8 * GB_ABLK;   // grid=128 -> 4096/iter, 4 iters

  for (int ag = gw * GB_ABLK; ag < NA; ag += stride) {
#pragma unroll
    for (int e = 0; e < GB_ABLK; ++e) h_s[wv][e][lane] = h[(ag + e) * 64 + lane];
    __syncthreads();
    const float4* h4 = reinterpret_cast<const float4*>(&h_s[wv][0][0]);
    float acc[9][GB_ABLK];
#pragma unroll
    for (int r = 0; r < 9; ++r)
#pragma unroll
      for (int e = 0; e < GB_ABLK; ++e) acc[r][e] = 0.f;
#pragma unroll 2
    for (int d4 = 0; d4 < 16; ++d4) {
      int sl = d4 ^ swz;
      float4 hv[GB_ABLK];
#pragma unroll
      for (int e = 0; e < GB_ABLK; ++e) hv[e] = h4[e * 16 + d4];
#pragma unroll
      for (int r = 0; r < 9; ++r) {
        float4 wr = w4[((r * 64 + lane) << 4) + sl];
#pragma unroll
        for (int e = 0; e < GB_ABLK; ++e) {
          acc[r][e] = fmaf(wr.x, hv[e].x, acc[r][e]);
          acc[r][e] = fmaf(wr.y, hv[e].y, acc[r][e]);
          acc[r][e] = fmaf(wr.z, hv[e].z, acc[r][e]);
          acc[r][e] = fmaf(wr.w, hv[e].w, acc[r][e]);
        }
      }
    }
#pragma unroll
    for (int r = 0; r < 9; ++r)
#pragma unroll
      for (int e = 0; e < GB_ABLK; ++e)
        g_store(&G[(size_t)(ag + e) * 576 + r * 64 + lane], acc[r][e]);
    __syncthreads();
  }
}

// ============ edge contraction + scatter-add ============
// msg[e,i=lane] = G[dst][512+i] + sum_k bf[e,k]*G[dst][k*64+i]; atomicAdd to agg[src].
#define EG_EBLK 8
template <typename GT>
__global__ __launch_bounds__(256) void k_edge_gather(
    const float* __restrict__ bf, const int* __restrict__ pairs,
    const GT* __restrict__ G, float* __restrict__ agg) {
  const int tid = threadIdx.x, lane = tid & 63, wv = tid >> 6;
  const int gw = blockIdx.x * 4 + wv;
  const int stride = gridDim.x * 4 * EG_EBLK;   // grid=1024 -> 32768/iter, 2 iters
  const int2* pairs2 = reinterpret_cast<const int2*>(pairs);

  for (int eg = gw * EG_EBLK; eg < NE; eg += stride) {
    float bval = bf[(eg + (lane >> 3)) * 8 + (lane & 7)];
    int2 p = make_int2(0, 0);
    if (lane < EG_EBLK) p = pairs2[eg + lane];
#pragma unroll 2
    for (int e = 0; e < EG_EBLK; ++e) {
      int src = __shfl(p.x, e, 64);
      int dst = __shfl(p.y, e, 64);
      const GT* g = G + (size_t)dst * 576;
      float acc = g_load(&g[512 + lane]);
#pragma unroll
      for (int k = 0; k < 8; ++k)
        acc = fmaf(__shfl(bval, e * 8 + k, 64), g_load(&g[k * 64 + lane]), acc);
      atomicAdd(&agg[src * 64 + lane], acc);
    }
  }
}

// ============ GRU cell (per atom) ============
#define GABLK 4
__global__ __launch_bounds__(512, 1) void k_gru(
    const float* __restrict__ agg, const float* __restrict__ wih,
    const float* __restrict__ whh, const float* __restrict__ bih,
    const float* __restrict__ bhh, float* __restrict__ h) {
  __shared__ __align__(16) float wih_s[192 * 64];
  __shared__ __align__(16) float whh_s[192 * 64];
  __shared__ __align__(16) float act_s[8][2][GABLK][64];
  const int tid = threadIdx.x, lane = tid & 63, wv = tid >> 6;

  for (int idx = tid; idx < 192 * 64; idx += 512) {
    int r = idx >> 6, d = idx & 63;
    int pos = (r << 6) + ((((d >> 2) ^ (r & 7)) << 2) | (d & 3));
    wih_s[pos] = wih[idx];
    whh_s[pos] = whh[idx];
  }
  __syncthreads();

  const float4* wi4 = reinterpret_cast<const float4*>(wih_s);
  const float4* wh4 = reinterpret_cast<const float4*>(whh_s);
  const float bir = bih[lane], biz = bih[64 + lane], bin_ = bih[128 + lane];
  const float bhr = bhh[lane], bhz = bhh[64 + lane], bhn = bhh[128 + lane];
  const int swz = lane & 7;
  const int gw = blockIdx.x * 8 + wv;
  const int stride = gridDim.x * 8 * GABLK;

  for (int ag = gw * GABLK; ag < NA; ag += stride) {
#pragma unroll
    for (int e = 0; e < GABLK; ++e) {
      act_s[wv][0][e][lane] = agg[(ag + e) * 64 + lane];
      act_s[wv][1][e][lane] = h[(ag + e) * 64 + lane];
    }
    __syncthreads();
    const float4* a4 = reinterpret_cast<const float4*>(&act_s[wv][0][0][0]);
    const float4* h4 = reinterpret_cast<const float4*>(&act_s[wv][1][0][0]);
    float air[GABLK] = {0,0,0,0}, aiz[GABLK] = {0,0,0,0}, ain[GABLK] = {0,0,0,0};
    float ahr[GABLK] = {0,0,0,0}, ahz[GABLK] = {0,0,0,0}, ahn[GABLK] = {0,0,0,0};
#pragma unroll 2
    for (int d4 = 0; d4 < 16; ++d4) {
      int sl = d4 ^ swz;
      float4 wir = wi4[(lane << 4) + sl];
      float4 wiz = wi4[((lane + 64) << 4) + sl];
      float4 win = wi4[((lane + 128) << 4) + sl];
      float4 whr = wh4[(lane << 4) + sl];
      float4 whz = wh4[((lane + 64) << 4) + sl];
      float4 whn = wh4[((lane + 128) << 4) + sl];
#pragma unroll
      for (int e = 0; e < GABLK; ++e) {
        float4 av = a4[e * 16 + d4];
        float4 hv = h4[e * 16 + d4];
        air[e] += wir.x*av.x + wir.y*av.y + wir.z*av.z + wir.w*av.w;
        aiz[e] += wiz.x*av.x + wiz.y*av.y + wiz.z*av.z + wiz.w*av.w;
        ain[e] += win.x*av.x + win.y*av.y + win.z*av.z + win.w*av.w;
        ahr[e] += whr.x*hv.x + whr.y*hv.y + whr.z*hv.z + whr.w*hv.w;
        ahz[e] += whz.x*hv.x + whz.y*hv.y + whz.z*hv.z + whz.w*hv.w;
        ahn[e] += whn.x*hv.x + whn.y*hv.y + whn.z*hv.z + whn.w*hv.w;
      }
    }
#pragma unroll
    for (int e = 0; e < GABLK; ++e) {
      float r = sigmoidf_((air[e] + bir) + (ahr[e] + bhr));
      float z = sigmoidf_((aiz[e] + biz) + (ahz[e] + bhz));
      float nn = tanhf((ain[e] + bin_) + r * (ahn[e] + bhn));
      float hold = act_s[wv][1][e][lane];
      h[(ag + e) * 64 + lane] = (1.0f - z) * nn + z * hold;
    }
    __syncthreads();
  }
}

// ============ qkv projection + valid mask ============
#define QABLK 4
__global__ __launch_bounds__(256, 1) void k_qkv(
    const float* __restrict__ h, const float* __restrict__ w,
    const float* __restrict__ b, float* __restrict__ qkv,
    int* __restrict__ valid) {
  __shared__ __align__(16) float w_s[192 * 64];
  __shared__ __align__(16) float x_s[4][QABLK][64];
  const int tid = threadIdx.x, lane = tid & 63, wv = tid >> 6;
  for (int idx = tid; idx < 192 * 64; idx += 256) {
    int r = idx >> 6, d = idx & 63;
    w_s[(r << 6) + ((((d >> 2) ^ (r & 7)) << 2) | (d & 3))] = w[idx];
  }
  __syncthreads();
  const float4* w4 = reinterpret_cast<const float4*>(w_s);
  const float bq = b[lane], bk = b[64 + lane], bv_ = b[128 + lane];
  const int swz = lane & 7;
  const int gw = blockIdx.x * 4 + wv;
  const int stride = gridDim.x * 4 * QABLK;
  for (int ag = gw * QABLK; ag < NA; ag += stride) {
#pragma unroll
    for (int e = 0; e < QABLK; ++e) x_s[wv][e][lane] = h[(ag + e) * 64 + lane];
    __syncthreads();
    const float4* x4 = reinterpret_cast<const float4*>(&x_s[wv][0][0]);
    float aq[QABLK] = {0,0,0,0}, ak[QABLK] = {0,0,0,0}, av_[QABLK] = {0,0,0,0};
    int nz[QABLK] = {0,0,0,0};
#pragma unroll 4
    for (int d4 = 0; d4 < 16; ++d4) {
      int sl = d4 ^ swz;
      float4 wq = w4[(lane << 4) + sl];
      float4 wk = w4[((lane + 64) << 4) + sl];
      float4 wvv = w4[((lane + 128) << 4) + sl];
#pragma unroll
      for (int e = 0; e < QABLK; ++e) {
        float4 xv = x4[e * 16 + d4];
        aq[e] += wq.x*xv.x + wq.y*xv.y + wq.z*xv.z + wq.w*xv.w;
        ak[e] += wk.x*xv.x + wk.y*xv.y + wk.z*xv.z + wk.w*xv.w;
        av_[e] += wvv.x*xv.x + wvv.y*xv.y + wvv.z*xv.z + wvv.w*xv.w;
        nz[e] |= (int)(xv.x != 0.f) | (int)(xv.y != 0.f) | (int)(xv.z != 0.f) | (int)(xv.w != 0.f);
      }
    }
#pragma unroll
    for (int e = 0; e < QABLK; ++e) {
      qkv[(ag + e) * 192 + lane] = aq[e] + bq;
      qkv[(ag + e) * 192 + 64 + lane] = ak[e] + bk;
      qkv[(ag + e) * 192 + 128 + lane] = av_[e] + bv_;
      if (lane == 0) valid[ag + e] = nz[e];
    }
    __syncthreads();
  }
}

// ============ attention: one wave per (molecule, head), online softmax ============
__global__ void k_attn(const float* __restrict__ qkv, const int* __restrict__ valid,
                       float* __restrict__ ao) {
  const int b = blockIdx.x >> 3, hh = blockIdx.x & 7;
  __shared__ float k_s[64][8];
  __shared__ float v_s[64][8];
  __shared__ int vd_s[64];
  const int lane = threadIdx.x;
  const int rowbase = (b * 64 + lane) * 192;
#pragma unroll
  for (int j = 0; j < 8; ++j) {
    k_s[lane][j] = qkv[rowbase + 64 + hh * 8 + j];
    v_s[lane][j] = qkv[rowbase + 128 + hh * 8 + j];
  }
  vd_s[lane] = valid[b * 64 + lane];
  __syncthreads();
  float q[8];
#pragma unroll
  for (int j = 0; j < 8; ++j) q[j] = qkv[rowbase + hh * 8 + j];
  float m = -3.0e38f, l = 0.f, o[8] = {0,0,0,0,0,0,0,0};
  for (int t = 0; t < 64; ++t) {
    float s = 0.f;
#pragma unroll
    for (int j = 0; j < 8; ++j) s += q[j] * k_s[t][j];
    s *= 0.35355339059327373f;
    s = vd_s[t] ? s : -1.0e9f;
    float mn = fmaxf(m, s);
    float c = expf(m - mn);
    float p = expf(s - mn);
    l = l * c + p;
#pragma unroll
    for (int j = 0; j < 8; ++j) o[j] = o[j] * c + p * v_s[t][j];
    m = mn;
  }
  const float inv = 1.0f / l;
  const int obase = (b * 64 + lane) * 64 + hh * 8;
#pragma unroll
  for (int j = 0; j < 8; ++j) ao[obase + j] = o[j] * inv;
}

// ============ out_proj + residual + LN1 ============
#define OABLK 4
__global__ __launch_bounds__(256, 1) void k_out_ln1(
    const float* __restrict__ x, const float* __restrict__ ao,
    const float* __restrict__ w, const float* __restrict__ bias,
    const float* __restrict__ g, const float* __restrict__ bb,
    float* __restrict__ y1) {
  __shared__ __align__(16) float w_s[64 * 64];
  __shared__ __align__(16) float a_s[4][OABLK][64];
  const int tid = threadIdx.x, lane = tid & 63, wv = tid >> 6;
  for (int idx = tid; idx < 64 * 64; idx += 256) {
    int r = idx >> 6, d = idx & 63;
    w_s[(r << 6) + ((((d >> 2) ^ (r & 7)) << 2) | (d & 3))] = w[idx];
  }
  __syncthreads();
  const float4* w4 = reinterpret_cast<const float4*>(w_s);
  const float bo = bias[lane], gg = g[lane], bbb = bb[lane];
  const int swz = lane & 7;
  const int gw = blockIdx.x * 4 + wv;
  const int stride = gridDim.x * 4 * OABLK;
  for (int ag = gw * OABLK; ag < NA; ag += stride) {
#pragma unroll
    for (int e = 0; e < OABLK; ++e) a_s[wv][e][lane] = ao[(ag + e) * 64 + lane];
    __syncthreads();
    const float4* a4 = reinterpret_cast<const float4*>(&a_s[wv][0][0]);
    float acc[OABLK] = {0,0,0,0};
#pragma unroll 4
    for (int d4 = 0; d4 < 16; ++d4) {
      int sl = d4 ^ swz;
      float4 wr = w4[(lane << 4) + sl];
#pragma unroll
      for (int e = 0; e < OABLK; ++e) {
        float4 av = a4[e * 16 + d4];
        acc[e] += wr.x*av.x + wr.y*av.y + wr.z*av.z + wr.w*av.w;
      }
    }
#pragma unroll
    for (int e = 0; e < OABLK; ++e) {
      float val = acc[e] + bo + x[(ag + e) * 64 + lane];
      float s1 = val, s2 = val * val;
#pragma unroll
      for (int mm = 1; mm < 64; mm <<= 1) {
        s1 += __shfl_xor(s1, mm, 64);
        s2 += __shfl_xor(s2, mm, 64);
      }
      float mu = s1 * 0.015625f;
      float var = s2 * 0.015625f - mu * mu;
      y1[(ag + e) * 64 + lane] = (val - mu) * rsqrtf(var + 1e-5f) * gg + bbb;
    }
    __syncthreads();
  }
}

// ============ FFN (512 hidden) + residual + LN2 ============
#define FABLK 4
__global__ __launch_bounds__(256, 1) void k_ffn(
    const float* __restrict__ y1, const float* __restrict__ w1,
    const float* __restrict__ b1, const float* __restrict__ w2,
    const float* __restrict__ b2, const float* __restrict__ g,
    const float* __restrict__ bb, float* __restrict__ y2) {
  __shared__ __align__(16) float hbuf[4][FABLK][512];
  __shared__ __align__(16) float y1_s[4][FABLK][64];
  const int tid = threadIdx.x, lane = tid & 63, wv = tid >> 6;
  float bb1[8];
#pragma unroll
  for (int cc = 0; cc < 8; ++cc) bb1[cc] = b1[cc * 64 + lane];
  const float b2v = b2[lane], gg = g[lane], bbb = bb[lane];
  const int gw = blockIdx.x * 4 + wv;
  const int stride = gridDim.x * 4 * FABLK;
  for (int ag = gw * FABLK; ag < NA; ag += stride) {
#pragma unroll
    for (int e = 0; e < FABLK; ++e) y1_s[wv][e][lane] = y1[(ag + e) * 64 + lane];
    __syncthreads();
    float hv[FABLK][8];
#pragma unroll
    for (int e = 0; e < FABLK; ++e)
#pragma unroll
      for (int cc = 0; cc < 8; ++cc) hv[e][cc] = bb1[cc];
#pragma unroll 4
    for (int d = 0; d < 64; ++d) {
      float w1v[8];
#pragma unroll
      for (int cc = 0; cc < 8; ++cc) w1v[cc] = w1[d * 512 + cc * 64 + lane];
#pragma unroll
      for (int e = 0; e < FABLK; ++e) {
        float yv = y1_s[wv][e][d];
#pragma unroll
        for (int cc = 0; cc < 8; ++cc) hv[e][cc] += yv * w1v[cc];
      }
    }
#pragma unroll
    for (int e = 0; e < FABLK; ++e)
#pragma unroll
      for (int cc = 0; cc < 8; ++cc)
        hbuf[wv][e][cc * 64 + lane] = fmaxf(hv[e][cc], 0.f);
    __syncthreads();
    float acc[FABLK] = {0,0,0,0};
    const float4* hb4 = reinterpret_cast<const float4*>(&hbuf[wv][0][0]);
#pragma unroll 4
    for (int c4 = 0; c4 < 128; ++c4) {
      float w2v[4];
#pragma unroll
      for (int qq = 0; qq < 4; ++qq) w2v[qq] = w2[(c4 * 4 + qq) * 64 + lane];
#pragma unroll
      for (int e = 0; e < FABLK; ++e) {
        float4 hq = hb4[e * 128 + c4];
        acc[e] += hq.x * w2v[0] + hq.y * w2v[1] + hq.z * w2v[2] + hq.w * w2v[3];
      }
    }
#pragma unroll
    for (int e = 0; e < FABLK; ++e) {
      float val = y1_s[wv][e][lane] + acc[e] + b2v;
      float s1 = val, s2 = val * val;
#pragma unroll
      for (int mm = 1; mm < 64; mm <<= 1) {
        s1 += __shfl_xor(s1, mm, 64);
        s2 += __shfl_xor(s2, mm, 64);
      }
      float mu = s1 * 0.015625f;
      float var = s2 * 0.015625f - mu * mu;
      y2[(ag + e) * 64 + lane] = (val - mu) * rsqrtf(var + 1e-5f) * gg + bbb;
    }
    __syncthreads();
  }
}

// ============ mean-pool over tokens ============
__global__ void k_pool(const float* __restrict__ y2, float* __restrict__ pooled) {
  const int b = blockIdx.x, lane = threadIdx.x;
  float s = 0.f;
  for (int t = 0; t < 64; ++t) s += y2[(b * 64 + t) * 64 + lane];
  pooled[b * 64 + lane] = s * 0.015625f;
}

// ============ readout head ============
__global__ __launch_bounds__(256) void k_head(
    const float* __restrict__ pooled, const float* __restrict__ d1w,
    const float* __restrict__ d1b, const float* __restrict__ d2w,
    const float* __restrict__ d2b, float* __restrict__ out) {
  const int b = blockIdx.x;
  __shared__ float p_s[64];
  __shared__ float red_s[4];
  const int tid = threadIdx.x;
  if (tid < 64) p_s[tid] = pooled[b * 64 + tid];
  __syncthreads();
  float acc = 0.f;
#pragma unroll
  for (int rep = 0; rep < 2; ++rep) {
    int c = rep * 256 + tid;
    float hvv = d1b[c];
    for (int d = 0; d < 64; ++d) hvv += p_s[d] * d1w[d * 512 + c];
    acc += fmaxf(hvv, 0.f) * d2w[c];
  }
#pragma unroll
  for (int mm = 1; mm < 64; mm <<= 1) acc += __shfl_xor(acc, mm, 64);
  if ((tid & 63) == 0) red_s[tid >> 6] = acc;
  __syncthreads();
  if (tid == 0) {
    float t = red_s[0] + red_s[1] + red_s[2] + red_s[3] + d2b[0];
    out[b] = 1.0f / (1.0f + expf(-t));
  }
}

extern "C" void kernel_launch(void* const* d_in, const int* in_sizes, int n_in,
                              void* d_out, int out_size, void* d_ws, size_t ws_size,
                              hipStream_t stream) {
  (void)in_sizes; (void)n_in; (void)out_size;
  const float* af   = (const float*)d_in[0];
  const float* bfeat= (const float*)d_in[1];
  const int*   pairs= (const int*)d_in[2];
  // d_in[3] = molecule_indicator (identity layout; unused)
  const float* kern = (const float*)d_in[4];
  const float* kbias= (const float*)d_in[5];
  const float* wih  = (const float*)d_in[6];
  const float* whh  = (const float*)d_in[7];
  const float* bih  = (const float*)d_in[8];
  const float* bhh  = (const float*)d_in[9];
  const float* ipw  = (const float*)d_in[10];
  const float* ipb  = (const float*)d_in[11];
  const float* opw  = (const float*)d_in[12];
  const float* opb  = (const float*)d_in[13];
  const float* fw1  = (const float*)d_in[14];
  const float* fb1  = (const float*)d_in[15];
  const float* fw2  = (const float*)d_in[16];
  const float* fb2  = (const float*)d_in[17];
  const float* l1g  = (const float*)d_in[18];
  const float* l1b  = (const float*)d_in[19];
  const float* l2g  = (const float*)d_in[20];
  const float* l2b  = (const float*)d_in[21];
  const float* d1w  = (const float*)d_in[22];
  const float* d1b  = (const float*)d_in[23];
  const float* d2w  = (const float*)d_in[24];
  const float* d2b  = (const float*)d_in[25];
  float* out = (float*)d_out;

  // workspace layout (floats)
  float* ws = (float*)d_ws;
  float* h      = ws;                              // 1,048,576
  float* agg    = h + (size_t)NA * 64;             // 1,048,576
  float* qkv    = agg + (size_t)NA * 64;           // 3,145,728
  float* ao     = qkv + (size_t)NA * 192;          // 1,048,576
  float* y1     = ao + (size_t)NA * 64;            // 1,048,576
  float* y2     = y1 + (size_t)NA * 64;            // 1,048,576
  float* pooled = y2 + (size_t)NA * 64;            // 16,384
  int*   valid  = (int*)(pooled + 256 * 64);       // 16,384
  size_t base_floats = (size_t)(valid + NA) - (size_t)ws;   // bytes of base layout

  // G: [NA x 576]. fp32 path appended after base layout if ws allows;
  // otherwise bf16 path aliased over qkv/ao/y1 (written only after MP loop).
  const size_t g_elems = (size_t)NA * 576;
  bool g32 = ws_size >= base_floats + g_elems * sizeof(float);
  float* G32 = (float*)((char*)d_ws + base_floats);
  __hip_bfloat16* G16 = (__hip_bfloat16*)qkv;

  k_init_h<<<NA * 64 / 256, 256, 0, stream>>>(af, h);
  for (int s = 0; s < 4; ++s) {
    hipMemsetAsync(agg, 0, (size_t)NA * 64 * sizeof(float), stream);
    if (g32) {
      k_gemm_G<float><<<128, 512, 0, stream>>>(h, kern, kbias, G32);
      k_edge_gather<float><<<1024, 256, 0, stream>>>(bfeat, pairs, G32, agg);
    } else {
      k_gemm_G<__hip_bfloat16><<<128, 512, 0, stream>>>(h, kern, kbias, G16);
      k_edge_gather<__hip_bfloat16><<<1024, 256, 0, stream>>>(bfeat, pairs, G16, agg);
    }
    k_gru<<<128, 512, 0, stream>>>(agg, wih, whh, bih, bhh, h);
  }
  k_qkv<<<256, 256, 0, stream>>>(h, ipw, ipb, qkv, valid);
  k_attn<<<2048, 64, 0, stream>>>(qkv, valid, ao);
  k_out_ln1<<<256, 256, 0, stream>>>(h, ao, opw, opb, l1g, l1b, y1);
  k_ffn<<<256, 256, 0, stream>>>(y1, fw1, fb1, fw2, fb2, l2g, l2b, y2);
  k_pool<<<256, 64, 0, stream>>>(y2, pooled);
  k_head<<<256, 256, 0, stream>>>(pooled, d1w, d1b, d2w, d2b, out);
}

// Round 4
// 511.693 us; speedup vs baseline: 3.8526x; 1.2830x over previous
//
#include <hip/hip_runtime.h>
#include <hip/hip_bf16.h>
#include <math.h>

#define NA 16384
#define NE 65536
#define AD 29

__device__ __forceinline__ float sigmoidf_(float x) { return 1.0f / (1.0f + expf(-x)); }

__device__ __forceinline__ float g_load(const float* p) { return *p; }
__device__ __forceinline__ float g_load(const __hip_bfloat16* p) { return __bfloat162float(*p); }
__device__ __forceinline__ void g_store(float* p, float v) { *p = v; }
__device__ __forceinline__ void g_store(__hip_bfloat16* p, float v) { *p = __float2bfloat16(v); }

// ============ init h: pad atom features 29 -> 64 ============
__global__ void k_init_h(const float* __restrict__ af, float* __restrict__ h) {
  int idx = blockIdx.x * 256 + threadIdx.x;
  if (idx >= NA * 64) return;
  int a = idx >> 6, d = idx & 63;
  h[idx] = (d < AD) ? af[a * AD + d] : 0.0f;
}

// ============ per-atom G precompute: G[a, k*64+i] = sum_j K[k][i*64+j]*h[a,j] ============
#define GB_ABLK 4
template <typename GT>
__global__ __launch_bounds__(512, 1) void k_gemm_G(
    const float* __restrict__ h, const float* __restrict__ kern,
    const float* __restrict__ kbias, GT* __restrict__ G) {
  __shared__ __align__(16) float w_s[576 * 64];          // 144 KB
  __shared__ __align__(16) float h_s[8][GB_ABLK][64];    // 8 KB
  const int tid = threadIdx.x, lane = tid & 63, wv = tid >> 6;

  for (int idx = tid; idx < 576 * 64; idx += 512) {
    int c = idx >> 6, j = idx & 63;
    float v = (c < 512) ? kern[((c >> 6) << 12) + ((c & 63) << 6) + j]
                        : kbias[((c & 63) << 6) + j];
    w_s[(c << 6) + ((((j >> 2) ^ (c & 7)) << 2) | (j & 3))] = v;
  }
  __syncthreads();

  const float4* w4 = reinterpret_cast<const float4*>(w_s);
  const int swz = lane & 7;
  const int gw = blockIdx.x * 8 + wv;
  const int stride = gridDim.x * 8 * GB_ABLK;   // grid=256 -> 8192/iter, 2 iters

  for (int ag = gw * GB_ABLK; ag < NA; ag += stride) {
#pragma unroll
    for (int e = 0; e < GB_ABLK; ++e) h_s[wv][e][lane] = h[(ag + e) * 64 + lane];
    __syncthreads();
    const float4* h4 = reinterpret_cast<const float4*>(&h_s[wv][0][0]);
    float acc[9][GB_ABLK];
#pragma unroll
    for (int r = 0; r < 9; ++r)
#pragma unroll
      for (int e = 0; e < GB_ABLK; ++e) acc[r][e] = 0.f;
#pragma unroll 2
    for (int d4 = 0; d4 < 16; ++d4) {
      int sl = d4 ^ swz;
      float4 hv[GB_ABLK];
#pragma unroll
      for (int e = 0; e < GB_ABLK; ++e) hv[e] = h4[e * 16 + d4];
#pragma unroll
      for (int r = 0; r < 9; ++r) {
        float4 wr = w4[((r * 64 + lane) << 4) + sl];
#pragma unroll
        for (int e = 0; e < GB_ABLK; ++e) {
          acc[r][e] = fmaf(wr.x, hv[e].x, acc[r][e]);
          acc[r][e] = fmaf(wr.y, hv[e].y, acc[r][e]);
          acc[r][e] = fmaf(wr.z, hv[e].z, acc[r][e]);
          acc[r][e] = fmaf(wr.w, hv[e].w, acc[r][e]);
        }
      }
    }
#pragma unroll
    for (int r = 0; r < 9; ++r)
#pragma unroll
      for (int e = 0; e < GB_ABLK; ++e)
        g_store(&G[(size_t)(ag + e) * 576 + r * 64 + lane], acc[r][e]);
    __syncthreads();
  }
}

// ============ edge contraction + scatter-add ============
#define EG_EBLK 8
template <typename GT>
__global__ __launch_bounds__(256) void k_edge_gather(
    const float* __restrict__ bf, const int* __restrict__ pairs,
    const GT* __restrict__ G, float* __restrict__ agg) {
  const int tid = threadIdx.x, lane = tid & 63, wv = tid >> 6;
  const int gw = blockIdx.x * 4 + wv;
  const int stride = gridDim.x * 4 * EG_EBLK;   // grid=2048 -> 65536/iter, 1 iter
  const int2* pairs2 = reinterpret_cast<const int2*>(pairs);

  for (int eg = gw * EG_EBLK; eg < NE; eg += stride) {
    float bval = bf[(eg + (lane >> 3)) * 8 + (lane & 7)];
    int2 p = make_int2(0, 0);
    if (lane < EG_EBLK) p = pairs2[eg + lane];
#pragma unroll 2
    for (int e = 0; e < EG_EBLK; ++e) {
      int src = __shfl(p.x, e, 64);
      int dst = __shfl(p.y, e, 64);
      const GT* g = G + (size_t)dst * 576;
      float acc = g_load(&g[512 + lane]);
#pragma unroll
      for (int k = 0; k < 8; ++k)
        acc = fmaf(__shfl(bval, e * 8 + k, 64), g_load(&g[k * 64 + lane]), acc);
      atomicAdd(&agg[src * 64 + lane], acc);
    }
  }
}

// ============ GRU cell (per atom) ============
#define GABLK 4
__global__ __launch_bounds__(512, 1) void k_gru(
    const float* __restrict__ agg, const float* __restrict__ wih,
    const float* __restrict__ whh, const float* __restrict__ bih,
    const float* __restrict__ bhh, float* __restrict__ h) {
  __shared__ __align__(16) float wih_s[192 * 64];
  __shared__ __align__(16) float whh_s[192 * 64];
  __shared__ __align__(16) float act_s[8][2][GABLK][64];
  const int tid = threadIdx.x, lane = tid & 63, wv = tid >> 6;

  for (int idx = tid; idx < 192 * 64; idx += 512) {
    int r = idx >> 6, d = idx & 63;
    int pos = (r << 6) + ((((d >> 2) ^ (r & 7)) << 2) | (d & 3));
    wih_s[pos] = wih[idx];
    whh_s[pos] = whh[idx];
  }
  __syncthreads();

  const float4* wi4 = reinterpret_cast<const float4*>(wih_s);
  const float4* wh4 = reinterpret_cast<const float4*>(whh_s);
  const float bir = bih[lane], biz = bih[64 + lane], bin_ = bih[128 + lane];
  const float bhr = bhh[lane], bhz = bhh[64 + lane], bhn = bhh[128 + lane];
  const int swz = lane & 7;
  const int gw = blockIdx.x * 8 + wv;
  const int stride = gridDim.x * 8 * GABLK;     // grid=256 -> 8192/iter, 2 iters

  for (int ag = gw * GABLK; ag < NA; ag += stride) {
#pragma unroll
    for (int e = 0; e < GABLK; ++e) {
      act_s[wv][0][e][lane] = agg[(ag + e) * 64 + lane];
      act_s[wv][1][e][lane] = h[(ag + e) * 64 + lane];
    }
    __syncthreads();
    const float4* a4 = reinterpret_cast<const float4*>(&act_s[wv][0][0][0]);
    const float4* h4 = reinterpret_cast<const float4*>(&act_s[wv][1][0][0]);
    float air[GABLK] = {0,0,0,0}, aiz[GABLK] = {0,0,0,0}, ain[GABLK] = {0,0,0,0};
    float ahr[GABLK] = {0,0,0,0}, ahz[GABLK] = {0,0,0,0}, ahn[GABLK] = {0,0,0,0};
#pragma unroll 2
    for (int d4 = 0; d4 < 16; ++d4) {
      int sl = d4 ^ swz;
      float4 wir = wi4[(lane << 4) + sl];
      float4 wiz = wi4[((lane + 64) << 4) + sl];
      float4 win = wi4[((lane + 128) << 4) + sl];
      float4 whr = wh4[(lane << 4) + sl];
      float4 whz = wh4[((lane + 64) << 4) + sl];
      float4 whn = wh4[((lane + 128) << 4) + sl];
#pragma unroll
      for (int e = 0; e < GABLK; ++e) {
        float4 av = a4[e * 16 + d4];
        float4 hv = h4[e * 16 + d4];
        air[e] += wir.x*av.x + wir.y*av.y + wir.z*av.z + wir.w*av.w;
        aiz[e] += wiz.x*av.x + wiz.y*av.y + wiz.z*av.z + wiz.w*av.w;
        ain[e] += win.x*av.x + win.y*av.y + win.z*av.z + win.w*av.w;
        ahr[e] += whr.x*hv.x + whr.y*hv.y + whr.z*hv.z + whr.w*hv.w;
        ahz[e] += whz.x*hv.x + whz.y*hv.y + whz.z*hv.z + whz.w*hv.w;
        ahn[e] += whn.x*hv.x + whn.y*hv.y + whn.z*hv.z + whn.w*hv.w;
      }
    }
#pragma unroll
    for (int e = 0; e < GABLK; ++e) {
      float r = sigmoidf_((air[e] + bir) + (ahr[e] + bhr));
      float z = sigmoidf_((aiz[e] + biz) + (ahz[e] + bhz));
      float nn = tanhf((ain[e] + bin_) + r * (ahn[e] + bhn));
      float hold = act_s[wv][1][e][lane];
      h[(ag + e) * 64 + lane] = (1.0f - z) * nn + z * hold;
    }
    __syncthreads();
  }
}

// ============ qkv projection + valid mask ============
#define QABLK 4
__global__ __launch_bounds__(256, 1) void k_qkv(
    const float* __restrict__ h, const float* __restrict__ w,
    const float* __restrict__ b, float* __restrict__ qkv,
    int* __restrict__ valid) {
  __shared__ __align__(16) float w_s[192 * 64];
  __shared__ __align__(16) float x_s[4][QABLK][64];
  const int tid = threadIdx.x, lane = tid & 63, wv = tid >> 6;
  for (int idx = tid; idx < 192 * 64; idx += 256) {
    int r = idx >> 6, d = idx & 63;
    w_s[(r << 6) + ((((d >> 2) ^ (r & 7)) << 2) | (d & 3))] = w[idx];
  }
  __syncthreads();
  const float4* w4 = reinterpret_cast<const float4*>(w_s);
  const float bq = b[lane], bk = b[64 + lane], bv_ = b[128 + lane];
  const int swz = lane & 7;
  const int gw = blockIdx.x * 4 + wv;
  const int stride = gridDim.x * 4 * QABLK;     // grid=512 -> 8192/iter, 2 iters
  for (int ag = gw * QABLK; ag < NA; ag += stride) {
#pragma unroll
    for (int e = 0; e < QABLK; ++e) x_s[wv][e][lane] = h[(ag + e) * 64 + lane];
    __syncthreads();
    const float4* x4 = reinterpret_cast<const float4*>(&x_s[wv][0][0]);
    float aq[QABLK] = {0,0,0,0}, ak[QABLK] = {0,0,0,0}, av_[QABLK] = {0,0,0,0};
    int nz[QABLK] = {0,0,0,0};
#pragma unroll 4
    for (int d4 = 0; d4 < 16; ++d4) {
      int sl = d4 ^ swz;
      float4 wq = w4[(lane << 4) + sl];
      float4 wk = w4[((lane + 64) << 4) + sl];
      float4 wvv = w4[((lane + 128) << 4) + sl];
#pragma unroll
      for (int e = 0; e < QABLK; ++e) {
        float4 xv = x4[e * 16 + d4];
        aq[e] += wq.x*xv.x + wq.y*xv.y + wq.z*xv.z + wq.w*xv.w;
        ak[e] += wk.x*xv.x + wk.y*xv.y + wk.z*xv.z + wk.w*xv.w;
        av_[e] += wvv.x*xv.x + wvv.y*xv.y + wvv.z*xv.z + wvv.w*xv.w;
        nz[e] |= (int)(xv.x != 0.f) | (int)(xv.y != 0.f) | (int)(xv.z != 0.f) | (int)(xv.w != 0.f);
      }
    }
#pragma unroll
    for (int e = 0; e < QABLK; ++e) {
      qkv[(ag + e) * 192 + lane] = aq[e] + bq;
      qkv[(ag + e) * 192 + 64 + lane] = ak[e] + bk;
      qkv[(ag + e) * 192 + 128 + lane] = av_[e] + bv_;
      if (lane == 0) valid[ag + e] = nz[e];
    }
    __syncthreads();
  }
}

// ============ attention: one wave per (molecule, head), online softmax ============
__global__ void k_attn(const float* __restrict__ qkv, const int* __restrict__ valid,
                       float* __restrict__ ao) {
  const int b = blockIdx.x >> 3, hh = blockIdx.x & 7;
  __shared__ float k_s[64][8];
  __shared__ float v_s[64][8];
  __shared__ int vd_s[64];
  const int lane = threadIdx.x;
  const int rowbase = (b * 64 + lane) * 192;
#pragma unroll
  for (int j = 0; j < 8; ++j) {
    k_s[lane][j] = qkv[rowbase + 64 + hh * 8 + j];
    v_s[lane][j] = qkv[rowbase + 128 + hh * 8 + j];
  }
  vd_s[lane] = valid[b * 64 + lane];
  __syncthreads();
  float q[8];
#pragma unroll
  for (int j = 0; j < 8; ++j) q[j] = qkv[rowbase + hh * 8 + j];
  float m = -3.0e38f, l = 0.f, o[8] = {0,0,0,0,0,0,0,0};
  for (int t = 0; t < 64; ++t) {
    float s = 0.f;
#pragma unroll
    for (int j = 0; j < 8; ++j) s += q[j] * k_s[t][j];
    s *= 0.35355339059327373f;
    s = vd_s[t] ? s : -1.0e9f;
    float mn = fmaxf(m, s);
    float c = expf(m - mn);
    float p = expf(s - mn);
    l = l * c + p;
#pragma unroll
    for (int j = 0; j < 8; ++j) o[j] = o[j] * c + p * v_s[t][j];
    m = mn;
  }
  const float inv = 1.0f / l;
  const int obase = (b * 64 + lane) * 64 + hh * 8;
#pragma unroll
  for (int j = 0; j < 8; ++j) ao[obase + j] = o[j] * inv;
}

// ============ out_proj + residual + LN1 ============
#define OABLK 4
__global__ __launch_bounds__(256, 1) void k_out_ln1(
    const float* __restrict__ x, const float* __restrict__ ao,
    const float* __restrict__ w, const float* __restrict__ bias,
    const float* __restrict__ g, const float* __restrict__ bb,
    float* __restrict__ y1) {
  __shared__ __align__(16) float w_s[64 * 64];
  __shared__ __align__(16) float a_s[4][OABLK][64];
  const int tid = threadIdx.x, lane = tid & 63, wv = tid >> 6;
  for (int idx = tid; idx < 64 * 64; idx += 256) {
    int r = idx >> 6, d = idx & 63;
    w_s[(r << 6) + ((((d >> 2) ^ (r & 7)) << 2) | (d & 3))] = w[idx];
  }
  __syncthreads();
  const float4* w4 = reinterpret_cast<const float4*>(w_s);
  const float bo = bias[lane], gg = g[lane], bbb = bb[lane];
  const int swz = lane & 7;
  const int gw = blockIdx.x * 4 + wv;
  const int stride = gridDim.x * 4 * OABLK;     // grid=512 -> 2 iters
  for (int ag = gw * OABLK; ag < NA; ag += stride) {
#pragma unroll
    for (int e = 0; e < OABLK; ++e) a_s[wv][e][lane] = ao[(ag + e) * 64 + lane];
    __syncthreads();
    const float4* a4 = reinterpret_cast<const float4*>(&a_s[wv][0][0]);
    float acc[OABLK] = {0,0,0,0};
#pragma unroll 4
    for (int d4 = 0; d4 < 16; ++d4) {
      int sl = d4 ^ swz;
      float4 wr = w4[(lane << 4) + sl];
#pragma unroll
      for (int e = 0; e < OABLK; ++e) {
        float4 av = a4[e * 16 + d4];
        acc[e] += wr.x*av.x + wr.y*av.y + wr.z*av.z + wr.w*av.w;
      }
    }
#pragma unroll
    for (int e = 0; e < OABLK; ++e) {
      float val = acc[e] + bo + x[(ag + e) * 64 + lane];
      float s1 = val, s2 = val * val;
#pragma unroll
      for (int mm = 1; mm < 64; mm <<= 1) {
        s1 += __shfl_xor(s1, mm, 64);
        s2 += __shfl_xor(s2, mm, 64);
      }
      float mu = s1 * 0.015625f;
      float var = s2 * 0.015625f - mu * mu;
      y1[(ag + e) * 64 + lane] = (val - mu) * rsqrtf(var + 1e-5f) * gg + bbb;
    }
    __syncthreads();
  }
}

// ============ weight transpose for FFN (into dead 'ao' region) ============
// w1t[c*64+d] = w1[d*512+c];  w2t[o*512+c] = w2[c*64+o]
__global__ void k_prep_w(const float* __restrict__ w1, const float* __restrict__ w2,
                         float* __restrict__ w1t, float* __restrict__ w2t) {
  int idx = blockIdx.x * 256 + threadIdx.x;
  if (idx >= 32768) return;
  int c = idx >> 6, d = idx & 63;
  w1t[idx] = w1[d * 512 + c];
  int o = idx >> 9, cc = idx & 511;
  w2t[idx] = w2[cc * 64 + o];
}

// ============ FFN (512 hidden) + residual + LN2, transposed weights ============
// lane owns hidden cols {cc*64+lane}; w1t/w2t rows are per-lane contiguous ->
// dwordx4 loads (4x fewer load instrs than round-3 dword version).
#define FABLK 4
__global__ __launch_bounds__(256, 1) void k_ffn(
    const float* __restrict__ y1, const float* __restrict__ w1t,
    const float* __restrict__ b1, const float* __restrict__ w2t,
    const float* __restrict__ b2, const float* __restrict__ g,
    const float* __restrict__ bb, float* __restrict__ y2) {
  __shared__ __align__(16) float hbuf[4][FABLK][512];   // 32 KB
  __shared__ __align__(16) float y1_s[4][FABLK][64];    // 4 KB
  const int tid = threadIdx.x, lane = tid & 63, wv = tid >> 6;
  float bb1[8];
#pragma unroll
  for (int cc = 0; cc < 8; ++cc) bb1[cc] = b1[cc * 64 + lane];
  const float b2v = b2[lane], gg = g[lane], bbb = bb[lane];
  const float4* w1t4 = reinterpret_cast<const float4*>(w1t);
  const float4* w2t4 = reinterpret_cast<const float4*>(w2t) + lane * 128;
  const int gw = blockIdx.x * 4 + wv;
  const int stride = gridDim.x * 4 * FABLK;   // grid=1024 -> 1 iter
  for (int ag = gw * FABLK; ag < NA; ag += stride) {
#pragma unroll
    for (int e = 0; e < FABLK; ++e) y1_s[wv][e][lane] = y1[(ag + e) * 64 + lane];
    __syncthreads();
    const float4* y14 = reinterpret_cast<const float4*>(&y1_s[wv][0][0]);
    float hv[FABLK][8];
#pragma unroll
    for (int e = 0; e < FABLK; ++e)
#pragma unroll
      for (int cc = 0; cc < 8; ++cc) hv[e][cc] = bb1[cc];
#pragma unroll 2
    for (int d4 = 0; d4 < 16; ++d4) {
      float4 yv[FABLK];
#pragma unroll
      for (int e = 0; e < FABLK; ++e) yv[e] = y14[e * 16 + d4];
#pragma unroll
      for (int cc = 0; cc < 8; ++cc) {
        float4 wr = w1t4[(cc * 64 + lane) * 16 + d4];
#pragma unroll
        for (int e = 0; e < FABLK; ++e) {
          hv[e][cc] = fmaf(wr.x, yv[e].x, hv[e][cc]);
          hv[e][cc] = fmaf(wr.y, yv[e].y, hv[e][cc]);
          hv[e][cc] = fmaf(wr.z, yv[e].z, hv[e][cc]);
          hv[e][cc] = fmaf(wr.w, yv[e].w, hv[e][cc]);
        }
      }
    }
#pragma unroll
    for (int e = 0; e < FABLK; ++e)
#pragma unroll
      for (int cc = 0; cc < 8; ++cc)
        hbuf[wv][e][cc * 64 + lane] = fmaxf(hv[e][cc], 0.f);
    __syncthreads();
    float acc[FABLK] = {0,0,0,0};
    const float4* hb4 = reinterpret_cast<const float4*>(&hbuf[wv][0][0]);
#pragma unroll 4
    for (int c4 = 0; c4 < 128; ++c4) {
      float4 w2v = w2t4[c4];
#pragma unroll
      for (int e = 0; e < FABLK; ++e) {
        float4 hq = hb4[e * 128 + c4];
        acc[e] = fmaf(hq.x, w2v.x, acc[e]);
        acc[e] = fmaf(hq.y, w2v.y, acc[e]);
        acc[e] = fmaf(hq.z, w2v.z, acc[e]);
        acc[e] = fmaf(hq.w, w2v.w, acc[e]);
      }
    }
#pragma unroll
    for (int e = 0; e < FABLK; ++e) {
      float val = y1_s[wv][e][lane] + acc[e] + b2v;
      float s1 = val, s2 = val * val;
#pragma unroll
      for (int mm = 1; mm < 64; mm <<= 1) {
        s1 += __shfl_xor(s1, mm, 64);
        s2 += __shfl_xor(s2, mm, 64);
      }
      float mu = s1 * 0.015625f;
      float var = s2 * 0.015625f - mu * mu;
      y2[(ag + e) * 64 + lane] = (val - mu) * rsqrtf(var + 1e-5f) * gg + bbb;
    }
    __syncthreads();
  }
}

// ============ mean-pool over tokens ============
__global__ void k_pool(const float* __restrict__ y2, float* __restrict__ pooled) {
  const int b = blockIdx.x, lane = threadIdx.x;
  float s = 0.f;
  for (int t = 0; t < 64; ++t) s += y2[(b * 64 + t) * 64 + lane];
  pooled[b * 64 + lane] = s * 0.015625f;
}

// ============ readout head ============
__global__ __launch_bounds__(256) void k_head(
    const float* __restrict__ pooled, const float* __restrict__ d1w,
    const float* __restrict__ d1b, const float* __restrict__ d2w,
    const float* __restrict__ d2b, float* __restrict__ out) {
  const int b = blockIdx.x;
  __shared__ float p_s[64];
  __shared__ float red_s[4];
  const int tid = threadIdx.x;
  if (tid < 64) p_s[tid] = pooled[b * 64 + tid];
  __syncthreads();
  float acc = 0.f;
#pragma unroll
  for (int rep = 0; rep < 2; ++rep) {
    int c = rep * 256 + tid;
    float hvv = d1b[c];
    for (int d = 0; d < 64; ++d) hvv += p_s[d] * d1w[d * 512 + c];
    acc += fmaxf(hvv, 0.f) * d2w[c];
  }
#pragma unroll
  for (int mm = 1; mm < 64; mm <<= 1) acc += __shfl_xor(acc, mm, 64);
  if ((tid & 63) == 0) red_s[tid >> 6] = acc;
  __syncthreads();
  if (tid == 0) {
    float t = red_s[0] + red_s[1] + red_s[2] + red_s[3] + d2b[0];
    out[b] = 1.0f / (1.0f + expf(-t));
  }
}

extern "C" void kernel_launch(void* const* d_in, const int* in_sizes, int n_in,
                              void* d_out, int out_size, void* d_ws, size_t ws_size,
                              hipStream_t stream) {
  (void)in_sizes; (void)n_in; (void)out_size;
  const float* af   = (const float*)d_in[0];
  const float* bfeat= (const float*)d_in[1];
  const int*   pairs= (const int*)d_in[2];
  // d_in[3] = molecule_indicator (identity layout; unused)
  const float* kern = (const float*)d_in[4];
  const float* kbias= (const float*)d_in[5];
  const float* wih  = (const float*)d_in[6];
  const float* whh  = (const float*)d_in[7];
  const float* bih  = (const float*)d_in[8];
  const float* bhh  = (const float*)d_in[9];
  const float* ipw  = (const float*)d_in[10];
  const float* ipb  = (const float*)d_in[11];
  const float* opw  = (const float*)d_in[12];
  const float* opb  = (const float*)d_in[13];
  const float* fw1  = (const float*)d_in[14];
  const float* fb1  = (const float*)d_in[15];
  const float* fw2  = (const float*)d_in[16];
  const float* fb2  = (const float*)d_in[17];
  const float* l1g  = (const float*)d_in[18];
  const float* l1b  = (const float*)d_in[19];
  const float* l2g  = (const float*)d_in[20];
  const float* l2b  = (const float*)d_in[21];
  const float* d1w  = (const float*)d_in[22];
  const float* d1b  = (const float*)d_in[23];
  const float* d2w  = (const float*)d_in[24];
  const float* d2b  = (const float*)d_in[25];
  float* out = (float*)d_out;

  // workspace layout (floats)
  float* ws = (float*)d_ws;
  float* h      = ws;
  float* agg    = h + (size_t)NA * 64;
  float* qkv    = agg + (size_t)NA * 64;
  float* ao     = qkv + (size_t)NA * 192;
  float* y1     = ao + (size_t)NA * 64;
  float* y2     = y1 + (size_t)NA * 64;
  float* pooled = y2 + (size_t)NA * 64;
  int*   valid  = (int*)(pooled + 256 * 64);
  size_t base_bytes = (size_t)((char*)(valid + NA) - (char*)ws);

  // G: [NA x 576]. fp32 path appended after base layout if ws allows;
  // otherwise bf16 path aliased over qkv/ao/y1 (written only after MP loop).
  const size_t g_elems = (size_t)NA * 576;
  bool g32 = ws_size >= base_bytes + g_elems * sizeof(float);
  float* G32 = (float*)((char*)d_ws + base_bytes);
  __hip_bfloat16* G16 = (__hip_bfloat16*)qkv;

  // FFN transposed weights live in the 'ao' region (dead after k_out_ln1).
  float* w1t = ao;
  float* w2t = ao + 32768;

  k_init_h<<<NA * 64 / 256, 256, 0, stream>>>(af, h);
  for (int s = 0; s < 4; ++s) {
    hipMemsetAsync(agg, 0, (size_t)NA * 64 * sizeof(float), stream);
    if (g32) {
      k_gemm_G<float><<<256, 512, 0, stream>>>(h, kern, kbias, G32);
      k_edge_gather<float><<<2048, 256, 0, stream>>>(bfeat, pairs, G32, agg);
    } else {
      k_gemm_G<__hip_bfloat16><<<256, 512, 0, stream>>>(h, kern, kbias, G16);
      k_edge_gather<__hip_bfloat16><<<2048, 256, 0, stream>>>(bfeat, pairs, G16, agg);
    }
    k_gru<<<256, 512, 0, stream>>>(agg, wih, whh, bih, bhh, h);
  }
  k_qkv<<<512, 256, 0, stream>>>(h, ipw, ipb, qkv, valid);
  k_attn<<<2048, 64, 0, stream>>>(qkv, valid, ao);
  k_out_ln1<<<512, 256, 0, stream>>>(h, ao, opw, opb, l1g, l1b, y1);
  k_prep_w<<<128, 256, 0, stream>>>(fw1, fw2, w1t, w2t);
  k_ffn<<<1024, 256, 0, stream>>>(y1, w1t, fb1, w2t, fb2, l2g, l2b, y2);
  k_pool<<<256, 64, 0, stream>>>(y2, pooled);
  k_head<<<256, 256, 0, stream>>>(pooled, d1w, d1b, d2w, d2b, out);
}

// Round 5
// 421.217 us; speedup vs baseline: 4.6801x; 1.2148x over previous
//
#include <hip/hip_runtime.h>
#include <hip/hip_bf16.h>
#include <math.h>

#define NA 16384
#define NE 65536
#define AD 29

__device__ __forceinline__ float sigmoidf_(float x) { return 1.0f / (1.0f + expf(-x)); }

__device__ __forceinline__ float g_load(const float* p) { return *p; }
__device__ __forceinline__ float g_load(const __hip_bfloat16* p) { return __bfloat162float(*p); }
__device__ __forceinline__ void g_store(float* p, float v) { *p = v; }
__device__ __forceinline__ void g_store(__hip_bfloat16* p, float v) { *p = __float2bfloat16(v); }

// ============ init h: pad atom features 29 -> 64 ============
__global__ void k_init_h(const float* __restrict__ af, float* __restrict__ h) {
  int idx = blockIdx.x * 256 + threadIdx.x;
  if (idx >= NA * 64) return;
  int a = idx >> 6, d = idx & 63;
  h[idx] = (d < AD) ? af[a * AD + d] : 0.0f;
}

// ============ per-atom G precompute: G[a, k*64+i] = sum_j K[k][i*64+j]*h[a,j] ============
// Also zeroes agg (fused; replaces a separate memset launch).
#define GB_ABLK 4
template <typename GT>
__global__ __launch_bounds__(512, 1) void k_gemm_G(
    const float* __restrict__ h, const float* __restrict__ kern,
    const float* __restrict__ kbias, GT* __restrict__ G,
    float* __restrict__ agg) {
  __shared__ __align__(16) float w_s[576 * 64];          // 144 KB
  __shared__ __align__(16) float h_s[8][GB_ABLK][64];    // 8 KB
  const int tid = threadIdx.x, lane = tid & 63, wv = tid >> 6;

  // fused agg zero (next kernel in stream accumulates into it)
  float4* agg4 = reinterpret_cast<float4*>(agg);
  for (int i = blockIdx.x * 512 + tid; i < NA * 16; i += gridDim.x * 512)
    agg4[i] = make_float4(0.f, 0.f, 0.f, 0.f);

  for (int idx = tid; idx < 576 * 64; idx += 512) {
    int c = idx >> 6, j = idx & 63;
    float v = (c < 512) ? kern[((c >> 6) << 12) + ((c & 63) << 6) + j]
                        : kbias[((c & 63) << 6) + j];
    w_s[(c << 6) + ((((j >> 2) ^ (c & 7)) << 2) | (j & 3))] = v;
  }
  __syncthreads();

  const float4* w4 = reinterpret_cast<const float4*>(w_s);
  const int swz = lane & 7;
  const int gw = blockIdx.x * 8 + wv;
  const int stride = gridDim.x * 8 * GB_ABLK;   // grid=256 -> 8192/iter, 2 iters

  for (int ag = gw * GB_ABLK; ag < NA; ag += stride) {
#pragma unroll
    for (int e = 0; e < GB_ABLK; ++e) h_s[wv][e][lane] = h[(ag + e) * 64 + lane];
    __syncthreads();
    const float4* h4 = reinterpret_cast<const float4*>(&h_s[wv][0][0]);
    float acc[9][GB_ABLK];
#pragma unroll
    for (int r = 0; r < 9; ++r)
#pragma unroll
      for (int e = 0; e < GB_ABLK; ++e) acc[r][e] = 0.f;
#pragma unroll 2
    for (int d4 = 0; d4 < 16; ++d4) {
      int sl = d4 ^ swz;
      float4 hv[GB_ABLK];
#pragma unroll
      for (int e = 0; e < GB_ABLK; ++e) hv[e] = h4[e * 16 + d4];
#pragma unroll
      for (int r = 0; r < 9; ++r) {
        float4 wr = w4[((r * 64 + lane) << 4) + sl];
#pragma unroll
        for (int e = 0; e < GB_ABLK; ++e) {
          acc[r][e] = fmaf(wr.x, hv[e].x, acc[r][e]);
          acc[r][e] = fmaf(wr.y, hv[e].y, acc[r][e]);
          acc[r][e] = fmaf(wr.z, hv[e].z, acc[r][e]);
          acc[r][e] = fmaf(wr.w, hv[e].w, acc[r][e]);
        }
      }
    }
#pragma unroll
    for (int r = 0; r < 9; ++r)
#pragma unroll
      for (int e = 0; e < GB_ABLK; ++e)
        g_store(&G[(size_t)(ag + e) * 576 + r * 64 + lane], acc[r][e]);
    __syncthreads();
  }
}

// ============ edge contraction + scatter-add ============
#define EG_EBLK 8
template <typename GT>
__global__ __launch_bounds__(256) void k_edge_gather(
    const float* __restrict__ bf, const int* __restrict__ pairs,
    const GT* __restrict__ G, float* __restrict__ agg) {
  const int tid = threadIdx.x, lane = tid & 63, wv = tid >> 6;
  const int gw = blockIdx.x * 4 + wv;
  const int stride = gridDim.x * 4 * EG_EBLK;   // grid=2048 -> 65536/iter, 1 iter
  const int2* pairs2 = reinterpret_cast<const int2*>(pairs);

  for (int eg = gw * EG_EBLK; eg < NE; eg += stride) {
    float bval = bf[(eg + (lane >> 3)) * 8 + (lane & 7)];
    int2 p = make_int2(0, 0);
    if (lane < EG_EBLK) p = pairs2[eg + lane];
#pragma unroll 2
    for (int e = 0; e < EG_EBLK; ++e) {
      int src = __shfl(p.x, e, 64);
      int dst = __shfl(p.y, e, 64);
      const GT* g = G + (size_t)dst * 576;
      float acc = g_load(&g[512 + lane]);
#pragma unroll
      for (int k = 0; k < 8; ++k)
        acc = fmaf(__shfl(bval, e * 8 + k, 64), g_load(&g[k * 64 + lane]), acc);
      atomicAdd(&agg[src * 64 + lane], acc);
    }
  }
}

// ============ GRU cell (per atom) ============
#define GABLK 4
__global__ __launch_bounds__(512, 1) void k_gru(
    const float* __restrict__ agg, const float* __restrict__ wih,
    const float* __restrict__ whh, const float* __restrict__ bih,
    const float* __restrict__ bhh, float* __restrict__ h) {
  __shared__ __align__(16) float wih_s[192 * 64];
  __shared__ __align__(16) float whh_s[192 * 64];
  __shared__ __align__(16) float act_s[8][2][GABLK][64];
  const int tid = threadIdx.x, lane = tid & 63, wv = tid >> 6;

  for (int idx = tid; idx < 192 * 64; idx += 512) {
    int r = idx >> 6, d = idx & 63;
    int pos = (r << 6) + ((((d >> 2) ^ (r & 7)) << 2) | (d & 3));
    wih_s[pos] = wih[idx];
    whh_s[pos] = whh[idx];
  }
  __syncthreads();

  const float4* wi4 = reinterpret_cast<const float4*>(wih_s);
  const float4* wh4 = reinterpret_cast<const float4*>(whh_s);
  const float bir = bih[lane], biz = bih[64 + lane], bin_ = bih[128 + lane];
  const float bhr = bhh[lane], bhz = bhh[64 + lane], bhn = bhh[128 + lane];
  const int swz = lane & 7;
  const int gw = blockIdx.x * 8 + wv;
  const int stride = gridDim.x * 8 * GABLK;     // grid=256 -> 8192/iter, 2 iters

  for (int ag = gw * GABLK; ag < NA; ag += stride) {
#pragma unroll
    for (int e = 0; e < GABLK; ++e) {
      act_s[wv][0][e][lane] = agg[(ag + e) * 64 + lane];
      act_s[wv][1][e][lane] = h[(ag + e) * 64 + lane];
    }
    __syncthreads();
    const float4* a4 = reinterpret_cast<const float4*>(&act_s[wv][0][0][0]);
    const float4* h4 = reinterpret_cast<const float4*>(&act_s[wv][1][0][0]);
    float air[GABLK] = {0,0,0,0}, aiz[GABLK] = {0,0,0,0}, ain[GABLK] = {0,0,0,0};
    float ahr[GABLK] = {0,0,0,0}, ahz[GABLK] = {0,0,0,0}, ahn[GABLK] = {0,0,0,0};
#pragma unroll 2
    for (int d4 = 0; d4 < 16; ++d4) {
      int sl = d4 ^ swz;
      float4 wir = wi4[(lane << 4) + sl];
      float4 wiz = wi4[((lane + 64) << 4) + sl];
      float4 win = wi4[((lane + 128) << 4) + sl];
      float4 whr = wh4[(lane << 4) + sl];
      float4 whz = wh4[((lane + 64) << 4) + sl];
      float4 whn = wh4[((lane + 128) << 4) + sl];
#pragma unroll
      for (int e = 0; e < GABLK; ++e) {
        float4 av = a4[e * 16 + d4];
        float4 hv = h4[e * 16 + d4];
        air[e] += wir.x*av.x + wir.y*av.y + wir.z*av.z + wir.w*av.w;
        aiz[e] += wiz.x*av.x + wiz.y*av.y + wiz.z*av.z + wiz.w*av.w;
        ain[e] += win.x*av.x + win.y*av.y + win.z*av.z + win.w*av.w;
        ahr[e] += whr.x*hv.x + whr.y*hv.y + whr.z*hv.z + whr.w*hv.w;
        ahz[e] += whz.x*hv.x + whz.y*hv.y + whz.z*hv.z + whz.w*hv.w;
        ahn[e] += whn.x*hv.x + whn.y*hv.y + whn.z*hv.z + whn.w*hv.w;
      }
    }
#pragma unroll
    for (int e = 0; e < GABLK; ++e) {
      float r = sigmoidf_((air[e] + bir) + (ahr[e] + bhr));
      float z = sigmoidf_((aiz[e] + biz) + (ahz[e] + bhz));
      float nn = tanhf((ain[e] + bin_) + r * (ahn[e] + bhn));
      float hold = act_s[wv][1][e][lane];
      h[(ag + e) * 64 + lane] = (1.0f - z) * nn + z * hold;
    }
    __syncthreads();
  }
}

// ============ qkv projection + valid mask ============
#define QABLK 4
__global__ __launch_bounds__(256, 1) void k_qkv(
    const float* __restrict__ h, const float* __restrict__ w,
    const float* __restrict__ b, float* __restrict__ qkv,
    int* __restrict__ valid) {
  __shared__ __align__(16) float w_s[192 * 64];
  __shared__ __align__(16) float x_s[4][QABLK][64];
  const int tid = threadIdx.x, lane = tid & 63, wv = tid >> 6;
  for (int idx = tid; idx < 192 * 64; idx += 256) {
    int r = idx >> 6, d = idx & 63;
    w_s[(r << 6) + ((((d >> 2) ^ (r & 7)) << 2) | (d & 3))] = w[idx];
  }
  __syncthreads();
  const float4* w4 = reinterpret_cast<const float4*>(w_s);
  const float bq = b[lane], bk = b[64 + lane], bv_ = b[128 + lane];
  const int swz = lane & 7;
  const int gw = blockIdx.x * 4 + wv;
  const int stride = gridDim.x * 4 * QABLK;     // grid=512 -> 8192/iter, 2 iters
  for (int ag = gw * QABLK; ag < NA; ag += stride) {
#pragma unroll
    for (int e = 0; e < QABLK; ++e) x_s[wv][e][lane] = h[(ag + e) * 64 + lane];
    __syncthreads();
    const float4* x4 = reinterpret_cast<const float4*>(&x_s[wv][0][0]);
    float aq[QABLK] = {0,0,0,0}, ak[QABLK] = {0,0,0,0}, av_[QABLK] = {0,0,0,0};
    int nz[QABLK] = {0,0,0,0};
#pragma unroll 4
    for (int d4 = 0; d4 < 16; ++d4) {
      int sl = d4 ^ swz;
      float4 wq = w4[(lane << 4) + sl];
      float4 wk = w4[((lane + 64) << 4) + sl];
      float4 wvv = w4[((lane + 128) << 4) + sl];
#pragma unroll
      for (int e = 0; e < QABLK; ++e) {
        float4 xv = x4[e * 16 + d4];
        aq[e] += wq.x*xv.x + wq.y*xv.y + wq.z*xv.z + wq.w*xv.w;
        ak[e] += wk.x*xv.x + wk.y*xv.y + wk.z*xv.z + wk.w*xv.w;
        av_[e] += wvv.x*xv.x + wvv.y*xv.y + wvv.z*xv.z + wvv.w*xv.w;
        nz[e] |= (int)(xv.x != 0.f) | (int)(xv.y != 0.f) | (int)(xv.z != 0.f) | (int)(xv.w != 0.f);
      }
    }
#pragma unroll
    for (int e = 0; e < QABLK; ++e) {
      qkv[(ag + e) * 192 + lane] = aq[e] + bq;
      qkv[(ag + e) * 192 + 64 + lane] = ak[e] + bk;
      qkv[(ag + e) * 192 + 128 + lane] = av_[e] + bv_;
      if (lane == 0) valid[ag + e] = nz[e];
    }
    __syncthreads();
  }
}

// ============ attention: one wave per (molecule, head), online softmax ============
__global__ void k_attn(const float* __restrict__ qkv, const int* __restrict__ valid,
                       float* __restrict__ ao) {
  const int b = blockIdx.x >> 3, hh = blockIdx.x & 7;
  __shared__ float k_s[64][8];
  __shared__ float v_s[64][8];
  __shared__ int vd_s[64];
  const int lane = threadIdx.x;
  const int rowbase = (b * 64 + lane) * 192;
#pragma unroll
  for (int j = 0; j < 8; ++j) {
    k_s[lane][j] = qkv[rowbase + 64 + hh * 8 + j];
    v_s[lane][j] = qkv[rowbase + 128 + hh * 8 + j];
  }
  vd_s[lane] = valid[b * 64 + lane];
  __syncthreads();
  float q[8];
#pragma unroll
  for (int j = 0; j < 8; ++j) q[j] = qkv[rowbase + hh * 8 + j];
  float m = -3.0e38f, l = 0.f, o[8] = {0,0,0,0,0,0,0,0};
  for (int t = 0; t < 64; ++t) {
    float s = 0.f;
#pragma unroll
    for (int j = 0; j < 8; ++j) s += q[j] * k_s[t][j];
    s *= 0.35355339059327373f;
    s = vd_s[t] ? s : -1.0e9f;
    float mn = fmaxf(m, s);
    float c = expf(m - mn);
    float p = expf(s - mn);
    l = l * c + p;
#pragma unroll
    for (int j = 0; j < 8; ++j) o[j] = o[j] * c + p * v_s[t][j];
    m = mn;
  }
  const float inv = 1.0f / l;
  const int obase = (b * 64 + lane) * 64 + hh * 8;
#pragma unroll
  for (int j = 0; j < 8; ++j) ao[obase + j] = o[j] * inv;
}

// ============ out_proj + residual + LN1 ============
#define OABLK 4
__global__ __launch_bounds__(256, 1) void k_out_ln1(
    const float* __restrict__ x, const float* __restrict__ ao,
    const float* __restrict__ w, const float* __restrict__ bias,
    const float* __restrict__ g, const float* __restrict__ bb,
    float* __restrict__ y1) {
  __shared__ __align__(16) float w_s[64 * 64];
  __shared__ __align__(16) float a_s[4][OABLK][64];
  const int tid = threadIdx.x, lane = tid & 63, wv = tid >> 6;
  for (int idx = tid; idx < 64 * 64; idx += 256) {
    int r = idx >> 6, d = idx & 63;
    w_s[(r << 6) + ((((d >> 2) ^ (r & 7)) << 2) | (d & 3))] = w[idx];
  }
  __syncthreads();
  const float4* w4 = reinterpret_cast<const float4*>(w_s);
  const float bo = bias[lane], gg = g[lane], bbb = bb[lane];
  const int swz = lane & 7;
  const int gw = blockIdx.x * 4 + wv;
  const int stride = gridDim.x * 4 * OABLK;     // grid=512 -> 2 iters
  for (int ag = gw * OABLK; ag < NA; ag += stride) {
#pragma unroll
    for (int e = 0; e < OABLK; ++e) a_s[wv][e][lane] = ao[(ag + e) * 64 + lane];
    __syncthreads();
    const float4* a4 = reinterpret_cast<const float4*>(&a_s[wv][0][0]);
    float acc[OABLK] = {0,0,0,0};
#pragma unroll 4
    for (int d4 = 0; d4 < 16; ++d4) {
      int sl = d4 ^ swz;
      float4 wr = w4[(lane << 4) + sl];
#pragma unroll
      for (int e = 0; e < OABLK; ++e) {
        float4 av = a4[e * 16 + d4];
        acc[e] += wr.x*av.x + wr.y*av.y + wr.z*av.z + wr.w*av.w;
      }
    }
#pragma unroll
    for (int e = 0; e < OABLK; ++e) {
      float val = acc[e] + bo + x[(ag + e) * 64 + lane];
      float s1 = val, s2 = val * val;
#pragma unroll
      for (int mm = 1; mm < 64; mm <<= 1) {
        s1 += __shfl_xor(s1, mm, 64);
        s2 += __shfl_xor(s2, mm, 64);
      }
      float mu = s1 * 0.015625f;
      float var = s2 * 0.015625f - mu * mu;
      y1[(ag + e) * 64 + lane] = (val - mu) * rsqrtf(var + 1e-5f) * gg + bbb;
    }
    __syncthreads();
  }
}

// ============ FFN (512 hidden) + residual + LN2 ============
// GEMM1: lane owns hidden cols {4l..4l+3, 256+4l..259+4l}; w1 read in its
// NATURAL [d][512] layout -> per d two float4 wave-loads with consecutive
// lanes at consecutive addresses (fully coalesced; round-4's strided-float4
// pattern touched 64 cache lines per load instr and stalled the TA).
// GEMM2: lane = output col; w2 natural [512][64] -> coalesced dwords; hidden
// broadcast from LDS. 8 atoms/wave, 72 KB LDS -> 2 blocks/CU.
#define FW 4
#define FABLK 8
__global__ __launch_bounds__(256, 2) void k_ffn(
    const float* __restrict__ y1, const float* __restrict__ w1,
    const float* __restrict__ b1, const float* __restrict__ w2,
    const float* __restrict__ b2, const float* __restrict__ g,
    const float* __restrict__ bb, float* __restrict__ y2) {
  __shared__ __align__(16) float hbuf[FW][FABLK][512];   // 64 KB
  __shared__ __align__(16) float y1_s[FW][FABLK][64];    // 8 KB
  const int tid = threadIdx.x, lane = tid & 63, wv = tid >> 6;
  const float4* w1_4 = reinterpret_cast<const float4*>(w1);
  const float4* b1_4 = reinterpret_cast<const float4*>(b1);
  const float b2v = b2[lane], gg = g[lane], bbb = bb[lane];
  const int gw = blockIdx.x * FW + wv;
  const int stride = gridDim.x * FW * FABLK;    // grid=512 -> 1 iter
  for (int ag = gw * FABLK; ag < NA; ag += stride) {
#pragma unroll
    for (int e = 0; e < FABLK; ++e) y1_s[wv][e][lane] = y1[(ag + e) * 64 + lane];
    __syncthreads();
    float4 hv0[FABLK], hv1[FABLK];
    const float4 bq0 = b1_4[lane], bq1 = b1_4[64 + lane];
#pragma unroll
    for (int e = 0; e < FABLK; ++e) { hv0[e] = bq0; hv1[e] = bq1; }
#pragma unroll 4
    for (int d = 0; d < 64; ++d) {
      float4 w0 = w1_4[d * 128 + lane];
      float4 w1v = w1_4[d * 128 + 64 + lane];
#pragma unroll
      for (int e = 0; e < FABLK; ++e) {
        float yv = y1_s[wv][e][d];
        hv0[e].x = fmaf(yv, w0.x, hv0[e].x);
        hv0[e].y = fmaf(yv, w0.y, hv0[e].y);
        hv0[e].z = fmaf(yv, w0.z, hv0[e].z);
        hv0[e].w = fmaf(yv, w0.w, hv0[e].w);
        hv1[e].x = fmaf(yv, w1v.x, hv1[e].x);
        hv1[e].y = fmaf(yv, w1v.y, hv1[e].y);
        hv1[e].z = fmaf(yv, w1v.z, hv1[e].z);
        hv1[e].w = fmaf(yv, w1v.w, hv1[e].w);
      }
    }
    float4* hb4w = reinterpret_cast<float4*>(&hbuf[wv][0][0]);
#pragma unroll
    for (int e = 0; e < FABLK; ++e) {
      float4 r0 = hv0[e], r1 = hv1[e];
      r0.x = fmaxf(r0.x, 0.f); r0.y = fmaxf(r0.y, 0.f);
      r0.z = fmaxf(r0.z, 0.f); r0.w = fmaxf(r0.w, 0.f);
      r1.x = fmaxf(r1.x, 0.f); r1.y = fmaxf(r1.y, 0.f);
      r1.z = fmaxf(r1.z, 0.f); r1.w = fmaxf(r1.w, 0.f);
      hb4w[e * 128 + lane] = r0;
      hb4w[e * 128 + 64 + lane] = r1;
    }
    __syncthreads();
    float acc[FABLK] = {0,0,0,0,0,0,0,0};
    const float4* hb4 = reinterpret_cast<const float4*>(&hbuf[wv][0][0]);
#pragma unroll 4
    for (int c4 = 0; c4 < 128; ++c4) {
      float w2v0 = w2[(c4 * 4 + 0) * 64 + lane];
      float w2v1 = w2[(c4 * 4 + 1) * 64 + lane];
      float w2v2 = w2[(c4 * 4 + 2) * 64 + lane];
      float w2v3 = w2[(c4 * 4 + 3) * 64 + lane];
#pragma unroll
      for (int e = 0; e < FABLK; ++e) {
        float4 hq = hb4[e * 128 + c4];
        acc[e] = fmaf(hq.x, w2v0, acc[e]);
        acc[e] = fmaf(hq.y, w2v1, acc[e]);
        acc[e] = fmaf(hq.z, w2v2, acc[e]);
        acc[e] = fmaf(hq.w, w2v3, acc[e]);
      }
    }
#pragma unroll
    for (int e = 0; e < FABLK; ++e) {
      float val = y1_s[wv][e][lane] + acc[e] + b2v;
      float s1 = val, s2 = val * val;
#pragma unroll
      for (int mm = 1; mm < 64; mm <<= 1) {
        s1 += __shfl_xor(s1, mm, 64);
        s2 += __shfl_xor(s2, mm, 64);
      }
      float mu = s1 * 0.015625f;
      float var = s2 * 0.015625f - mu * mu;
      y2[(ag + e) * 64 + lane] = (val - mu) * rsqrtf(var + 1e-5f) * gg + bbb;
    }
    __syncthreads();
  }
}

// ============ mean-pool over tokens ============
__global__ void k_pool(const float* __restrict__ y2, float* __restrict__ pooled) {
  const int b = blockIdx.x, lane = threadIdx.x;
  float s = 0.f;
  for (int t = 0; t < 64; ++t) s += y2[(b * 64 + t) * 64 + lane];
  pooled[b * 64 + lane] = s * 0.015625f;
}

// ============ readout head ============
__global__ __launch_bounds__(256) void k_head(
    const float* __restrict__ pooled, const float* __restrict__ d1w,
    const float* __restrict__ d1b, const float* __restrict__ d2w,
    const float* __restrict__ d2b, float* __restrict__ out) {
  const int b = blockIdx.x;
  __shared__ float p_s[64];
  __shared__ float red_s[4];
  const int tid = threadIdx.x;
  if (tid < 64) p_s[tid] = pooled[b * 64 + tid];
  __syncthreads();
  float acc = 0.f;
#pragma unroll
  for (int rep = 0; rep < 2; ++rep) {
    int c = rep * 256 + tid;
    float hvv = d1b[c];
    for (int d = 0; d < 64; ++d) hvv += p_s[d] * d1w[d * 512 + c];
    acc += fmaxf(hvv, 0.f) * d2w[c];
  }
#pragma unroll
  for (int mm = 1; mm < 64; mm <<= 1) acc += __shfl_xor(acc, mm, 64);
  if ((tid & 63) == 0) red_s[tid >> 6] = acc;
  __syncthreads();
  if (tid == 0) {
    float t = red_s[0] + red_s[1] + red_s[2] + red_s[3] + d2b[0];
    out[b] = 1.0f / (1.0f + expf(-t));
  }
}

extern "C" void kernel_launch(void* const* d_in, const int* in_sizes, int n_in,
                              void* d_out, int out_size, void* d_ws, size_t ws_size,
                              hipStream_t stream) {
  (void)in_sizes; (void)n_in; (void)out_size;
  const float* af   = (const float*)d_in[0];
  const float* bfeat= (const float*)d_in[1];
  const int*   pairs= (const int*)d_in[2];
  // d_in[3] = molecule_indicator (identity layout; unused)
  const float* kern = (const float*)d_in[4];
  const float* kbias= (const float*)d_in[5];
  const float* wih  = (const float*)d_in[6];
  const float* whh  = (const float*)d_in[7];
  const float* bih  = (const float*)d_in[8];
  const float* bhh  = (const float*)d_in[9];
  const float* ipw  = (const float*)d_in[10];
  const float* ipb  = (const float*)d_in[11];
  const float* opw  = (const float*)d_in[12];
  const float* opb  = (const float*)d_in[13];
  const float* fw1  = (const float*)d_in[14];
  const float* fb1  = (const float*)d_in[15];
  const float* fw2  = (const float*)d_in[16];
  const float* fb2  = (const float*)d_in[17];
  const float* l1g  = (const float*)d_in[18];
  const float* l1b  = (const float*)d_in[19];
  const float* l2g  = (const float*)d_in[20];
  const float* l2b  = (const float*)d_in[21];
  const float* d1w  = (const float*)d_in[22];
  const float* d1b  = (const float*)d_in[23];
  const float* d2w  = (const float*)d_in[24];
  const float* d2b  = (const float*)d_in[25];
  float* out = (float*)d_out;

  // workspace layout (floats)
  float* ws = (float*)d_ws;
  float* h      = ws;
  float* agg    = h + (size_t)NA * 64;
  float* qkv    = agg + (size_t)NA * 64;
  float* ao     = qkv + (size_t)NA * 192;
  float* y1     = ao + (size_t)NA * 64;
  float* y2     = y1 + (size_t)NA * 64;
  float* pooled = y2 + (size_t)NA * 64;
  int*   valid  = (int*)(pooled + 256 * 64);
  size_t base_bytes = (size_t)((char*)(valid + NA) - (char*)ws);

  // G: [NA x 576]. fp32 path appended after base layout if ws allows;
  // otherwise bf16 path aliased over qkv/ao/y1 (written only after MP loop).
  const size_t g_elems = (size_t)NA * 576;
  bool g32 = ws_size >= base_bytes + g_elems * sizeof(float);
  float* G32 = (float*)((char*)d_ws + base_bytes);
  __hip_bfloat16* G16 = (__hip_bfloat16*)qkv;

  k_init_h<<<NA * 64 / 256, 256, 0, stream>>>(af, h);
  for (int s = 0; s < 4; ++s) {
    if (g32) {
      k_gemm_G<float><<<256, 512, 0, stream>>>(h, kern, kbias, G32, agg);
      k_edge_gather<float><<<2048, 256, 0, stream>>>(bfeat, pairs, G32, agg);
    } else {
      k_gemm_G<__hip_bfloat16><<<256, 512, 0, stream>>>(h, kern, kbias, G16, agg);
      k_edge_gather<__hip_bfloat16><<<2048, 256, 0, stream>>>(bfeat, pairs, G16, agg);
    }
    k_gru<<<256, 512, 0, stream>>>(agg, wih, whh, bih, bhh, h);
  }
  k_qkv<<<512, 256, 0, stream>>>(h, ipw, ipb, qkv, valid);
  k_attn<<<2048, 64, 0, stream>>>(qkv, valid, ao);
  k_out_ln1<<<512, 256, 0, stream>>>(h, ao, opw, opb, l1g, l1b, y1);
  k_ffn<<<512, 256, 0, stream>>>(y1, fw1, fb1, fw2, fb2, l2g, l2b, y2);
  k_pool<<<256, 64, 0, stream>>>(y2, pooled);
  k_head<<<256, 256, 0, stream>>>(pooled, d1w, d1b, d2w, d2b, out);
}